// Round 5
// baseline (2292.358 us; speedup 1.0000x reference)
//
#include <hip/hip_runtime.h>
#include <hip/hip_bf16.h>
#include <math.h>

#define HIDDEN 256
#define NPTS 8192
#define NMID_L 9
#define NU_C 0.01f

typedef __attribute__((ext_vector_type(8))) short bf16x8;
typedef __attribute__((ext_vector_type(4))) float floatx4;

// ---------- bf16 helpers (manual RNE, no API dependence) ----------
__device__ __forceinline__ ushort f2b(float a) {
    unsigned x = __float_as_uint(a);
    unsigned r = (x + 0x7fffu + ((x >> 16) & 1u)) >> 16;
    return (ushort)r;
}
__device__ __forceinline__ float b2f(ushort u) {
    return __uint_as_float(((unsigned)u) << 16);
}
__device__ __forceinline__ void split2(float a, ushort& hi, ushort& lo) {
    ushort h = f2b(a);
    lo = f2b(a - b2f(h));
    hi = h;
}

// softplus100 value + first three derivatives
__device__ __forceinline__ void act_derivs(float z, float& h, float& s1, float& s2, float& s3)
{
    float t = 100.0f * z;
    float s, sp;
    if (t >= 0.0f) {
        float e = __expf(-t);
        s = 1.0f / (1.0f + e);
        sp = t + log1pf(e);
    } else {
        float e = __expf(t);
        s = e / (1.0f + e);
        sp = log1pf(e);
    }
    h  = 0.01f * sp;
    s1 = s;
    s2 = 100.0f * s * (1.0f - s);
    s3 = s2 * (100.0f - 200.0f * s);
}

// ---------- weight prep: W[k][n] -> Wt_hi/lo[n][k] (transpose + split), 18 layers ----------
__global__ __launch_bounds__(256) void wprep(const float* __restrict__ psi_Wm,
                                             const float* __restrict__ p_Wm,
                                             ushort* __restrict__ Wth, ushort* __restrict__ Wtl)
{
    int bid = blockIdx.x;
    int l = bid >> 4;           // 0..17
    int tile = bid & 15;
    int tk = (tile >> 2) * 64;
    int tn = (tile & 3) * 64;
    const float* W = (l < 9) ? (psi_Wm + (size_t)l * 65536)
                             : (p_Wm + (size_t)(l - 9) * 65536);
    __shared__ float tileS[64][65];
    int t = threadIdx.x;
    #pragma unroll
    for (int i = 0; i < 16; ++i) {
        int r = i * 4 + (t >> 6);
        int c = t & 63;
        tileS[r][c] = W[(size_t)(tk + r) * HIDDEN + tn + c];
    }
    __syncthreads();
    ushort* oh = Wth + (size_t)l * 65536;
    ushort* ol = Wtl + (size_t)l * 65536;
    #pragma unroll
    for (int i = 0; i < 16; ++i) {
        int n = i * 4 + (t >> 6);
        int k = t & 63;
        float a = tileS[k][n];
        ushort hh, ll; split2(a, hh, ll);
        oh[(size_t)(tn + n) * HIDDEN + tk + k] = hh;
        ol[(size_t)(tn + n) * HIDDEN + tk + k] = ll;
    }
}

// ---------- layer 0: jet init, writes hi/lo planes ----------
template<int C>
__global__ void jet_init(const float* __restrict__ x, const float* __restrict__ y,
                         const float* __restrict__ W0, const float* __restrict__ b0,
                         ushort* __restrict__ Jh, ushort* __restrict__ Jl, int n0, int nc)
{
    int idx = blockIdx.x * blockDim.x + threadIdx.x;
    if (idx >= nc * HIDDEN) return;
    int p = idx >> 8;
    int j = idx & 255;
    int gp = n0 + p;
    float ax = W0[j];
    float ay = W0[HIDDEN + j];
    float a = x[gp] * ax + y[gp] * ay + b0[j];
    float h, s1, s2, s3;
    act_derivs(a, h, s1, s2, s3);
    float vals[C];
    vals[0] = h; vals[1] = s1 * ax; vals[2] = s1 * ay;
    if constexpr (C == 10) {
        vals[3] = s2 * ax * ax;
        vals[4] = s2 * ax * ay;
        vals[5] = s2 * ay * ay;
        vals[6] = s3 * ax * ax * ax;
        vals[7] = s3 * ax * ax * ay;
        vals[8] = s3 * ax * ay * ay;
        vals[9] = s3 * ay * ay * ay;
    }
    size_t PL = (size_t)nc * HIDDEN;
    size_t base = (size_t)p * HIDDEN + j;
    #pragma unroll
    for (int c = 0; c < C; ++c) {
        ushort hh, ll; split2(vals[c], hh, ll);
        Jh[c * PL + base] = hh;
        Jl[c * PL + base] = ll;
    }
}

// ---------- MFMA hidden layer ----------
// Block: 512 thr = 8 waves; 16 points x 256 cols; wave w owns cols [32w,32w+32).
// M-tiles = C jet comps of the same 16 points -> chain rule thread-local in acc[c].
template<int C>
__global__ __launch_bounds__(512, 4) void jet_layer_mfma(
    const ushort* __restrict__ Jh, const ushort* __restrict__ Jl,
    const ushort* __restrict__ Wth, const ushort* __restrict__ Wtl,
    const float* __restrict__ b,
    ushort* __restrict__ Oh, ushort* __restrict__ Ol, int nc)
{
    __shared__ bf16x8 ldsA[2 * C * 64];   // [hi/lo][comp][lane] fragment-order, 2C KB
    const int t = threadIdx.x;
    const int lane = t & 63;
    const int wv = t >> 6;
    const int p0 = blockIdx.x * 16;
    const int wn0 = wv * 32;
    const size_t PL = (size_t)nc * HIDDEN;

    floatx4 acc[C][2];
    #pragma unroll
    for (int c = 0; c < C; ++c) {
        acc[c][0] = (floatx4){0.f, 0.f, 0.f, 0.f};
        acc[c][1] = (floatx4){0.f, 0.f, 0.f, 0.f};
    }

    const bf16x8* WthV = (const bf16x8*)Wth;
    const bf16x8* WtlV = (const bf16x8*)Wtl;

    for (int ch = 0; ch < 8; ++ch) {
        const int kc = ch * 32;
        // stage A-fragments for this chunk into registers (coalesced 64B rows)
        bf16x8 sreg[3];
        int sg[3];
        int nstage = 0;
        for (int g = t; g < 2 * C * 64; g += 512) {
            int pl = g >> 6;          // plane: 0..C-1 hi, C..2C-1 lo
            int slot = g & 63;        // (slot&15)=row, (slot>>4)=k-slot
            const ushort* plane = (pl < C) ? (Jh + (size_t)pl * PL)
                                           : (Jl + (size_t)(pl - C) * PL);
            const ushort* gp = plane + (size_t)(p0 + (slot & 15)) * HIDDEN
                             + kc + (slot >> 4) * 8;
            sreg[nstage] = *(const bf16x8*)gp;
            sg[nstage] = g;
            ++nstage;
        }
        __syncthreads();              // prev chunk's frag reads done
        for (int i = 0; i < nstage; ++i)
            ldsA[sg[i]] = sreg[i];
        // B-fragments (from pre-transposed weights; L2/L1-resident)
        const int bk = kc >> 3;
        bf16x8 bh[2], bl[2];
        #pragma unroll
        for (int tt = 0; tt < 2; ++tt) {
            size_t bi = (size_t)(wn0 + tt * 16 + (lane & 15)) * 32 + bk + (lane >> 4);
            bh[tt] = WthV[bi];
            bl[tt] = WtlV[bi];
        }
        __syncthreads();              // LDS visible (barrier drains counters)
        #pragma unroll
        for (int c = 0; c < C; ++c) {
            bf16x8 ah = ldsA[c * 64 + lane];
            bf16x8 al = ldsA[(C + c) * 64 + lane];
            #pragma unroll
            for (int tt = 0; tt < 2; ++tt) {
                acc[c][tt] = __builtin_amdgcn_mfma_f32_16x16x32_bf16(ah, bh[tt], acc[c][tt], 0, 0, 0);
                acc[c][tt] = __builtin_amdgcn_mfma_f32_16x16x32_bf16(ah, bl[tt], acc[c][tt], 0, 0, 0);
                acc[c][tt] = __builtin_amdgcn_mfma_f32_16x16x32_bf16(al, bh[tt], acc[c][tt], 0, 0, 0);
            }
        }
    }

    // epilogue: chain rule, split, store
    float bc[2];
    bc[0] = b[wn0 + (lane & 15)];
    bc[1] = b[wn0 + 16 + (lane & 15)];
    #pragma unroll
    for (int tt = 0; tt < 2; ++tt) {
        #pragma unroll
        for (int r = 0; r < 4; ++r) {
            float z = acc[0][tt][r] + bc[tt];
            float h, s1, s2, s3;
            act_derivs(z, h, s1, s2, s3);
            float outv[C];
            float ax = acc[1][tt][r], ay = acc[2][tt][r];
            outv[0] = h;
            outv[1] = s1 * ax;
            outv[2] = s1 * ay;
            if constexpr (C == 10) {
                float axx = acc[3][tt][r], axy = acc[4][tt][r], ayy = acc[5][tt][r];
                float axxx = acc[6][tt][r], axxy = acc[7][tt][r];
                float axyy = acc[8][tt][r], ayyy = acc[9][tt][r];
                outv[3] = s2 * ax * ax + s1 * axx;
                outv[4] = s2 * ax * ay + s1 * axy;
                outv[5] = s2 * ay * ay + s1 * ayy;
                outv[6] = s3 * ax * ax * ax + 3.f * s2 * ax * axx + s1 * axxx;
                outv[7] = s3 * ax * ax * ay + s2 * (2.f * ax * axy + ay * axx) + s1 * axxy;
                outv[8] = s3 * ax * ay * ay + s2 * (2.f * ay * axy + ax * ayy) + s1 * axyy;
                outv[9] = s3 * ay * ay * ay + 3.f * s2 * ay * ayy + s1 * ayyy;
            }
            int row = p0 + (lane >> 4) * 4 + r;
            int col = wn0 + tt * 16 + (lane & 15);
            size_t base = (size_t)row * HIDDEN + col;
            #pragma unroll
            for (int c = 0; c < C; ++c) {
                ushort hh, ll; split2(outv[c], hh, ll);
                Oh[c * PL + base] = hh;
                Ol[c * PL + base] = ll;
            }
        }
    }
}

// ---------- final linear dots (psi: 9 derivative comps) ----------
__global__ void dots_psi(const ushort* __restrict__ Jh, const ushort* __restrict__ Jl,
                         const float* __restrict__ Wl, float* __restrict__ P, int n0, int nc)
{
    int lane = threadIdx.x & 63;
    int p = blockIdx.x * 4 + (threadIdx.x >> 6);
    size_t PL = (size_t)nc * HIDDEN;
    float4 wl = reinterpret_cast<const float4*>(Wl)[lane];
    #pragma unroll
    for (int c = 1; c < 10; ++c) {
        ushort4 h4 = ((const ushort4*)(Jh + c * PL + (size_t)p * HIDDEN))[lane];
        ushort4 l4 = ((const ushort4*)(Jl + c * PL + (size_t)p * HIDDEN))[lane];
        float s = (b2f(h4.x) + b2f(l4.x)) * wl.x + (b2f(h4.y) + b2f(l4.y)) * wl.y
                + (b2f(h4.z) + b2f(l4.z)) * wl.z + (b2f(h4.w) + b2f(l4.w)) * wl.w;
        #pragma unroll
        for (int off = 32; off; off >>= 1) s += __shfl_down(s, off, 64);
        if (lane == 0) P[(size_t)(n0 + p) * 16 + (c - 1)] = s;
    }
}

__global__ void dots_p(const ushort* __restrict__ Jh, const ushort* __restrict__ Jl,
                       const float* __restrict__ Wl, const float* __restrict__ bl,
                       float* __restrict__ P, int n0, int nc)
{
    int lane = threadIdx.x & 63;
    int p = blockIdx.x * 4 + (threadIdx.x >> 6);
    size_t PL = (size_t)nc * HIDDEN;
    float4 wl = reinterpret_cast<const float4*>(Wl)[lane];
    #pragma unroll
    for (int c = 0; c < 3; ++c) {
        ushort4 h4 = ((const ushort4*)(Jh + c * PL + (size_t)p * HIDDEN))[lane];
        ushort4 l4 = ((const ushort4*)(Jl + c * PL + (size_t)p * HIDDEN))[lane];
        float s = (b2f(h4.x) + b2f(l4.x)) * wl.x + (b2f(h4.y) + b2f(l4.y)) * wl.y
                + (b2f(h4.z) + b2f(l4.z)) * wl.z + (b2f(h4.w) + b2f(l4.w)) * wl.w;
        #pragma unroll
        for (int off = 32; off; off >>= 1) s += __shfl_down(s, off, 64);
        if (lane == 0) P[(size_t)(n0 + p) * 16 + 9 + c] = s + (c == 0 ? bl[0] : 0.f);
    }
}

// ---------- loss ----------
__global__ __launch_bounds__(256) void loss_partials(
    const float* __restrict__ P, const float* __restrict__ u,
    const float* __restrict__ v, const float* __restrict__ pr,
    const int* __restrict__ mask, float* __restrict__ partials)
{
    int i = blockIdx.x * 256 + threadIdx.x;
    float s[9];
    #pragma unroll
    for (int k = 0; k < 9; ++k) s[k] = 0.f;
    if (i < NPTS) {
        const float* Pi = P + (size_t)i * 16;
        float psix = Pi[0], psiy = Pi[1], psixx = Pi[2], psixy = Pi[3], psiyy = Pi[4];
        float psixxx = Pi[5], psixxy = Pi[6], psixyy = Pi[7], psiyyy = Pi[8];
        float pv = Pi[9], ppx = Pi[10], ppy = Pi[11];
        float up = psiy, vp = -psix;
        float u_x = psixy, u_y = psiyy, v_x = -psixx, v_y = -psixy;
        float u_xx = psixxy, u_yy = psiyyy, v_xx = -psixxx, v_yy = -psixyy;
        float f_u = 2.f * up * u_x + up * v_y + vp * u_y + ppx - NU_C * (u_xx + u_yy);
        float f_v = 2.f * vp * v_y + up * v_x + vp * u_x + ppy - NU_C * (v_xx + v_yy);
        float ut = u[i], vt = v[i], pt = pr[i];
        float m = mask[i] ? 1.f : 0.f;
        float du = ut - up, dv = vt - vp, dp = pt - pv;
        s[0] = m * du * du; s[1] = m * dv * dv; s[2] = m * dp * dp;
        s[3] = du * du;     s[4] = dv * dv;     s[5] = dp * dp;
        s[6] = f_u * f_u;   s[7] = f_v * f_v;   s[8] = m;
    }
    int lane = threadIdx.x & 63, wid = threadIdx.x >> 6;
    __shared__ float red[4][9];
    #pragma unroll
    for (int k = 0; k < 9; ++k) {
        float xv = s[k];
        #pragma unroll
        for (int off = 32; off; off >>= 1) xv += __shfl_down(xv, off, 64);
        s[k] = xv;
    }
    if (lane == 0) {
        #pragma unroll
        for (int k = 0; k < 9; ++k) red[wid][k] = s[k];
    }
    __syncthreads();
    if (threadIdx.x == 0) {
        #pragma unroll
        for (int k = 0; k < 9; ++k)
            partials[blockIdx.x * 9 + k] = red[0][k] + red[1][k] + red[2][k] + red[3][k];
    }
}

__global__ void loss_final(const float* __restrict__ partials, float* __restrict__ out)
{
    int lane = threadIdx.x;
    float sums[9];
    #pragma unroll
    for (int k = 0; k < 9; ++k) {
        float xv = (lane < 32) ? partials[lane * 9 + k] : 0.f;
        #pragma unroll
        for (int off = 32; off; off >>= 1) xv += __shfl_down(xv, off, 64);
        sums[k] = xv;
    }
    if (lane == 0) {
        float ms = fmaxf(sums[8], 1.0f);
        float inv_n = 1.0f / (float)NPTS;
        float u_bc = sums[0] / ms, v_bc = sums[1] / ms, p_bc = sums[2] / ms;
        float u_tr = sums[3] * inv_n, v_tr = sums[4] * inv_n, p_tr = sums[5] * inv_n;
        float rans = sums[6] * inv_n + sums[7] * inv_n;
        out[0] = u_bc + v_bc + rans;
        out[1] = p_bc + rans;
        out[2] = u_tr;
        out[3] = v_tr;
        out[4] = p_tr;
        out[5] = rans;
    }
}

extern "C" void kernel_launch(void* const* d_in, const int* in_sizes, int n_in,
                              void* d_out, int out_size, void* d_ws, size_t ws_size,
                              hipStream_t stream)
{
    (void)in_sizes; (void)n_in; (void)out_size;
    const float* x    = (const float*)d_in[0];
    const float* y    = (const float*)d_in[1];
    const float* u    = (const float*)d_in[2];
    const float* v    = (const float*)d_in[3];
    const float* pr   = (const float*)d_in[4];
    const int*   mask = (const int*)d_in[5];
    const float* psi_W0 = (const float*)d_in[6];
    const float* psi_b0 = (const float*)d_in[7];
    const float* psi_Wm = (const float*)d_in[8];
    const float* psi_bm = (const float*)d_in[9];
    const float* psi_Wl = (const float*)d_in[10];
    // d_in[11] = psi_bl: unused (psi value never enters the loss)
    const float* p_W0 = (const float*)d_in[12];
    const float* p_b0 = (const float*)d_in[13];
    const float* p_Wm = (const float*)d_in[14];
    const float* p_bm = (const float*)d_in[15];
    const float* p_Wl = (const float*)d_in[16];
    const float* p_bl = (const float*)d_in[17];

    float*  P        = (float*)d_ws;                 // NPTS*16
    float*  partials = P + (size_t)NPTS * 16;        // 512
    ushort* Wth      = (ushort*)(partials + 512);    // 18*65536
    ushort* Wtl      = Wth + (size_t)18 * 65536;
    ushort* jets     = Wtl + (size_t)18 * 65536;

    size_t head = ((size_t)NPTS * 16 + 512) * sizeof(float)
                + (size_t)2 * 18 * 65536 * sizeof(ushort);
    size_t avail = ws_size > head ? ws_size - head : 0;
    int nc = NPTS;
    while (nc > 256 && (size_t)4 * 10 * nc * HIDDEN * sizeof(ushort) > avail) nc >>= 1;

    size_t PLm = (size_t)10 * nc * HIDDEN;
    ushort* Ah = jets;
    ushort* Al = Ah + PLm;
    ushort* Bh = Al + PLm;
    ushort* Bl = Bh + PLm;

    wprep<<<288, 256, 0, stream>>>(psi_Wm, p_Wm, Wth, Wtl);

    for (int n0 = 0; n0 < NPTS; n0 += nc) {
        // --- psi net: 10 jet comps ---
        jet_init<10><<<(nc * HIDDEN) / 256, 256, 0, stream>>>(x, y, psi_W0, psi_b0, Ah, Al, n0, nc);
        ushort *ch_ = Ah, *cl_ = Al, *nh_ = Bh, *nl_ = Bl;
        for (int l = 0; l < NMID_L; ++l) {
            jet_layer_mfma<10><<<nc / 16, 512, 0, stream>>>(
                ch_, cl_, Wth + (size_t)l * 65536, Wtl + (size_t)l * 65536,
                psi_bm + (size_t)l * HIDDEN, nh_, nl_, nc);
            ushort* t1 = ch_; ch_ = nh_; nh_ = t1;
            ushort* t2 = cl_; cl_ = nl_; nl_ = t2;
        }
        dots_psi<<<nc / 4, 256, 0, stream>>>(ch_, cl_, psi_Wl, P, n0, nc);

        // --- p net: 3 jet comps ---
        jet_init<3><<<(nc * HIDDEN) / 256, 256, 0, stream>>>(x, y, p_W0, p_b0, Ah, Al, n0, nc);
        ch_ = Ah; cl_ = Al; nh_ = Bh; nl_ = Bl;
        for (int l = 0; l < NMID_L; ++l) {
            jet_layer_mfma<3><<<nc / 16, 512, 0, stream>>>(
                ch_, cl_, Wth + (size_t)(9 + l) * 65536, Wtl + (size_t)(9 + l) * 65536,
                p_bm + (size_t)l * HIDDEN, nh_, nl_, nc);
            ushort* t1 = ch_; ch_ = nh_; nh_ = t1;
            ushort* t2 = cl_; cl_ = nl_; nl_ = t2;
        }
        dots_p<<<nc / 4, 256, 0, stream>>>(ch_, cl_, p_Wl, p_bl, P, n0, nc);
    }

    loss_partials<<<NPTS / 256, 256, 0, stream>>>(P, u, v, pr, mask, partials);
    loss_final<<<1, 64, 0, stream>>>(partials, (float*)d_out);
}

// Round 6
// 707.649 us; speedup vs baseline: 3.2394x; 3.2394x over previous
//
#include <hip/hip_runtime.h>
#include <hip/hip_bf16.h>
#include <math.h>

#define HIDDEN 256
#define NPTS 8192
#define NMID_L 9
#define NU_C 0.01f

typedef __attribute__((ext_vector_type(8))) short bf16x8;
typedef __attribute__((ext_vector_type(4))) float floatx4;

// ---------- bf16 helpers ----------
__device__ __forceinline__ ushort f2b(float a) {
    unsigned x = __float_as_uint(a);
    return (ushort)((x + 0x7fffu + ((x >> 16) & 1u)) >> 16);
}
__device__ __forceinline__ float b2f(ushort u) {
    return __uint_as_float(((unsigned)u) << 16);
}
__device__ __forceinline__ void split2(float a, ushort& hi, ushort& lo) {
    ushort h = f2b(a);
    lo = f2b(a - b2f(h));
    hi = h;
}

// softplus100 value + first three derivatives
__device__ __forceinline__ void act_derivs(float z, float& h, float& s1, float& s2, float& s3)
{
    float t = 100.0f * z;
    float s, sp;
    if (t >= 0.0f) {
        float e = __expf(-t);
        s = 1.0f / (1.0f + e);
        sp = t + log1pf(e);
    } else {
        float e = __expf(t);
        s = e / (1.0f + e);
        sp = log1pf(e);
    }
    h  = 0.01f * sp;
    s1 = s;
    s2 = 100.0f * s * (1.0f - s);
    s3 = s2 * (100.0f - 200.0f * s);
}

// ---------- weight prep: W[k][n] -> B-fragment layout, split hi/lo ----------
// Granule index: (((l*8 + w)*2 + tt)*8 + ch)*64 + ks*16 + col  holds
// (n = w*32 + tt*16 + col, k = ch*32 + ks*8 + e), e = 0..7.
__global__ __launch_bounds__(256) void wprep(const float* __restrict__ psi_Wm,
                                             const float* __restrict__ p_Wm,
                                             ushort* __restrict__ Wfh, ushort* __restrict__ Wfl)
{
    int bid = blockIdx.x;
    int l = bid >> 4;            // 0..17
    int tile = bid & 15;
    int tk = (tile >> 2) * 64;
    int tn = (tile & 3) * 64;
    const float* W = (l < 9) ? (psi_Wm + (size_t)l * 65536)
                             : (p_Wm + (size_t)(l - 9) * 65536);
    __shared__ float tileS[64][65];
    int t = threadIdx.x;
    #pragma unroll
    for (int i = 0; i < 16; ++i) {
        int r = i * 4 + (t >> 6);
        int c = t & 63;
        tileS[r][c] = W[(size_t)(tk + r) * HIDDEN + tn + c];
    }
    __syncthreads();
    bf16x8* oh = (bf16x8*)Wfh;
    bf16x8* ol = (bf16x8*)Wfl;
    #pragma unroll
    for (int i = 0; i < 2; ++i) {
        int g = i * 256 + t;          // 0..511 granules of this 64x64 tile
        int n_loc = g >> 3;
        int kg = g & 7;
        int n = tn + n_loc;
        int k0 = tk + kg * 8;
        int w = n >> 5, tt = (n >> 4) & 1, col = n & 15;
        int ch = k0 >> 5, ks = (k0 >> 3) & 3;
        size_t fidx = ((((size_t)l * 8 + w) * 2 + tt) * 8 + ch) * 64 + ks * 16 + col;
        bf16x8 vh, vl;
        #pragma unroll
        for (int e = 0; e < 8; ++e) {
            ushort hh, ll;
            split2(tileS[kg * 8 + e][n_loc], hh, ll);
            vh[e] = (short)hh;
            vl[e] = (short)ll;
        }
        oh[fidx] = vh;
        ol[fidx] = vl;
    }
}

// ---------- fused whole-net kernel ----------
// 512 threads = 8 waves; block owns 16 points. Full jet state lives in LDS:
// region (c, ch) = 2 KB at smem + (c*8+ch)*2048; hi frag granules [0,1024),
// lo [1024,2048). A-frag: lane&15 = point, lane>>4 = k-granule (proven r5 layout).
// Wave w produces output cols [32w,32w+32) = exactly state chunk w -> wave-private
// transpose via f32 bounce in its own region (rotated 32B blocks, p>>2).
template<int C, int DF, int DN, int PB, bool ADDBL>
__global__ __launch_bounds__(512, 2) void fused_net(
    const float* __restrict__ x, const float* __restrict__ y,
    const float* __restrict__ W0, const float* __restrict__ b0,
    const ushort* __restrict__ Wfh, const ushort* __restrict__ Wfl,
    const float* __restrict__ bm,
    const float* __restrict__ Wl, const float* __restrict__ bl,
    float* __restrict__ P)
{
    extern __shared__ char smem[];
    const int t = threadIdx.x;
    const int lane = t & 63;
    const int wv = t >> 6;
    const int p0 = blockIdx.x * 16;

    // ---- layer 0: jet init directly into state (wave w fills chunk w) ----
    {
        float xx = x[p0 + (lane & 15)];
        float yy = y[p0 + (lane & 15)];
        bf16x8 vh[C], vl[C];
        #pragma unroll
        for (int e = 0; e < 8; ++e) {
            int j = wv * 32 + ((lane >> 4) << 3) + e;
            float ax = W0[j];
            float ay = W0[HIDDEN + j];
            float a = xx * ax + yy * ay + b0[j];
            float h, s1, s2, s3;
            act_derivs(a, h, s1, s2, s3);
            float vals[C];
            vals[0] = h; vals[1] = s1 * ax; vals[2] = s1 * ay;
            if constexpr (C == 10) {
                vals[3] = s2 * ax * ax;
                vals[4] = s2 * ax * ay;
                vals[5] = s2 * ay * ay;
                vals[6] = s3 * ax * ax * ax;
                vals[7] = s3 * ax * ax * ay;
                vals[8] = s3 * ax * ay * ay;
                vals[9] = s3 * ay * ay * ay;
            }
            #pragma unroll
            for (int c = 0; c < C; ++c) {
                ushort hh, ll;
                split2(vals[c], hh, ll);
                vh[c][e] = (short)hh;
                vl[c][e] = (short)ll;
            }
        }
        #pragma unroll
        for (int c = 0; c < C; ++c) {
            char* R = smem + (c * 8 + wv) * 2048;
            *(bf16x8*)(R + lane * 16) = vh[c];
            *(bf16x8*)(R + 1024 + lane * 16) = vl[c];
        }
    }
    __syncthreads();

    const bf16x8* WfhV = (const bf16x8*)Wfh;
    const bf16x8* WflV = (const bf16x8*)Wfl;

    // ---- 9 hidden layers ----
    for (int l = 0; l < NMID_L; ++l) {
        floatx4 acc[C][2];
        #pragma unroll
        for (int c = 0; c < C; ++c) {
            acc[c][0] = (floatx4){0.f, 0.f, 0.f, 0.f};
            acc[c][1] = (floatx4){0.f, 0.f, 0.f, 0.f};
        }
        const size_t wbase = ((size_t)l * 8 + wv) * 1024;   // granules
        for (int ch = 0; ch < 8; ++ch) {
            bf16x8 bh[2], blo[2];
            #pragma unroll
            for (int tt = 0; tt < 2; ++tt) {
                size_t bi = wbase + ((size_t)tt * 8 + ch) * 64 + lane;
                bh[tt] = WfhV[bi];
                blo[tt] = WflV[bi];
            }
            #pragma unroll
            for (int c = 0; c < C; ++c) {
                const char* rb = smem + (c * 8 + ch) * 2048 + lane * 16;
                bf16x8 ah = *(const bf16x8*)rb;
                bf16x8 al = *(const bf16x8*)(rb + 1024);
                #pragma unroll
                for (int tt = 0; tt < 2; ++tt) {
                    acc[c][tt] = __builtin_amdgcn_mfma_f32_16x16x32_bf16(ah, bh[tt], acc[c][tt], 0, 0, 0);
                    acc[c][tt] = __builtin_amdgcn_mfma_f32_16x16x32_bf16(ah, blo[tt], acc[c][tt], 0, 0, 0);
                    acc[c][tt] = __builtin_amdgcn_mfma_f32_16x16x32_bf16(al, bh[tt], acc[c][tt], 0, 0, 0);
                }
            }
        }
        __syncthreads();   // all waves done reading state for this layer

        // epilogue: bias + activation derivatives (thread-local)
        float bb[2];
        bb[0] = bm[l * 256 + wv * 32 + (lane & 15)];
        bb[1] = bm[l * 256 + wv * 32 + 16 + (lane & 15)];
        float hv[2][4], s1v[2][4], s2v[2][4], s3v[2][4];
        #pragma unroll
        for (int tt = 0; tt < 2; ++tt)
        #pragma unroll
        for (int r = 0; r < 4; ++r) {
            float z = acc[0][tt][r] + bb[tt];
            act_derivs(z, hv[tt][r], s1v[tt][r], s2v[tt][r], s3v[tt][r]);
        }

        // per-comp chain rule + wave-private transpose bounce
        #pragma unroll
        for (int c = 0; c < C; ++c) {
            float ov[2][4];
            #pragma unroll
            for (int tt = 0; tt < 2; ++tt)
            #pragma unroll
            for (int r = 0; r < 4; ++r) {
                float s1 = s1v[tt][r], s2 = s2v[tt][r], s3 = s3v[tt][r];
                float ax = acc[1][tt][r], ay = acc[2][tt][r];
                float val;
                if (c == 0) val = hv[tt][r];
                else if (c == 1) val = s1 * ax;
                else if (c == 2) val = s1 * ay;
                else if constexpr (C == 10) {
                    float axx = acc[3][tt][r], axy = acc[4][tt][r], ayy = acc[5][tt][r];
                    float axxx = acc[6][tt][r], axxy = acc[7][tt][r];
                    float axyy = acc[8][tt][r], ayyy = acc[9][tt][r];
                    if (c == 3) val = s2 * ax * ax + s1 * axx;
                    else if (c == 4) val = s2 * ax * ay + s1 * axy;
                    else if (c == 5) val = s2 * ay * ay + s1 * ayy;
                    else if (c == 6) val = s3 * ax * ax * ax + 3.f * s2 * ax * axx + s1 * axxx;
                    else if (c == 7) val = s3 * ax * ax * ay + s2 * (2.f * ax * axy + ay * axx) + s1 * axxy;
                    else if (c == 8) val = s3 * ax * ay * ay + s2 * (2.f * ay * axy + ax * ayy) + s1 * axyy;
                    else val = s3 * ay * ay * ay + 3.f * s2 * ay * ayy + s1 * ayyy;
                } else val = 0.f;
                ov[tt][r] = val;
            }
            char* R = smem + (c * 8 + wv) * 2048;
            // phase 1: f32 scatter into wave-private region (rotated 32B blocks)
            #pragma unroll
            for (int tt = 0; tt < 2; ++tt)
            #pragma unroll
            for (int r = 0; r < 4; ++r) {
                int p = ((lane >> 4) << 2) + r;
                int cl = tt * 16 + (lane & 15);
                int rblk = ((cl >> 3) + (p >> 2)) & 3;
                *(float*)(R + p * 128 + rblk * 32 + (cl & 7) * 4) = ov[tt][r];
            }
            // phase 2: read back in A-frag order (wave-synchronous; compiler
            // keeps ds order via may-alias + inserts lgkm waits)
            {
                int p = lane & 15, ks = lane >> 4;
                int rblk = (ks + (p >> 2)) & 3;
                const char* src = R + p * 128 + rblk * 32;
                floatx4 f0 = *(const floatx4*)src;
                floatx4 f1 = *(const floatx4*)(src + 16);
                bf16x8 nh, nl;
                #pragma unroll
                for (int e = 0; e < 4; ++e) {
                    ushort hh, ll;
                    split2(f0[e], hh, ll);
                    nh[e] = (short)hh; nl[e] = (short)ll;
                }
                #pragma unroll
                for (int e = 0; e < 4; ++e) {
                    ushort hh, ll;
                    split2(f1[e], hh, ll);
                    nh[4 + e] = (short)hh; nl[4 + e] = (short)ll;
                }
                // phase 3: store final bf16 hi/lo frags (overwrites scratch)
                *(bf16x8*)(R + lane * 16) = nh;
                *(bf16x8*)(R + 1024 + lane * 16) = nl;
            }
        }
        __syncthreads();   // state fully updated for next layer
    }

    // ---- final linear dots ----
    {
        float4 w0 = ((const float4*)Wl)[wv * 8 + (lane >> 4) * 2];
        float4 w1 = ((const float4*)Wl)[wv * 8 + (lane >> 4) * 2 + 1];
        float part[DN];
        #pragma unroll
        for (int i = 0; i < DN; ++i) {
            int c = DF + i;
            const char* rb = smem + (c * 8 + wv) * 2048 + lane * 16;
            bf16x8 vh = *(const bf16x8*)rb;
            bf16x8 vl = *(const bf16x8*)(rb + 1024);
            float s = 0.f;
            #pragma unroll
            for (int e = 0; e < 4; ++e)
                s += (b2f((ushort)vh[e]) + b2f((ushort)vl[e])) * (&w0.x)[e];
            #pragma unroll
            for (int e = 0; e < 4; ++e)
                s += (b2f((ushort)vh[4 + e]) + b2f((ushort)vl[4 + e])) * (&w1.x)[e];
            s += __shfl_xor(s, 16, 64);
            s += __shfl_xor(s, 32, 64);
            part[i] = s;
        }
        __syncthreads();   // all state reads done before scratch overwrite (c0 region)
        if (lane < 16) {
            float* sc = (float*)(smem + wv * 2048);
            #pragma unroll
            for (int i = 0; i < DN; ++i) sc[i * 16 + lane] = part[i];
        }
        __syncthreads();
        if (t < 16 * DN) {
            int p = t & 15, i = t >> 4;
            float s = 0.f;
            #pragma unroll
            for (int w = 0; w < 8; ++w)
                s += ((const float*)(smem + w * 2048))[i * 16 + p];
            if (ADDBL && i == 0) s += bl[0];
            P[(size_t)(p0 + p) * 16 + PB + i] = s;
        }
    }
}

// ---------- loss ----------
__global__ __launch_bounds__(256) void loss_partials(
    const float* __restrict__ P, const float* __restrict__ u,
    const float* __restrict__ v, const float* __restrict__ pr,
    const int* __restrict__ mask, float* __restrict__ partials)
{
    int i = blockIdx.x * 256 + threadIdx.x;
    float s[9];
    #pragma unroll
    for (int k = 0; k < 9; ++k) s[k] = 0.f;
    if (i < NPTS) {
        const float* Pi = P + (size_t)i * 16;
        float psix = Pi[0], psiy = Pi[1], psixx = Pi[2], psixy = Pi[3], psiyy = Pi[4];
        float psixxx = Pi[5], psixxy = Pi[6], psixyy = Pi[7], psiyyy = Pi[8];
        float pv = Pi[9], ppx = Pi[10], ppy = Pi[11];
        float up = psiy, vp = -psix;
        float u_x = psixy, u_y = psiyy, v_x = -psixx, v_y = -psixy;
        float u_xx = psixxy, u_yy = psiyyy, v_xx = -psixxx, v_yy = -psixyy;
        float f_u = 2.f * up * u_x + up * v_y + vp * u_y + ppx - NU_C * (u_xx + u_yy);
        float f_v = 2.f * vp * v_y + up * v_x + vp * u_x + ppy - NU_C * (v_xx + v_yy);
        float ut = u[i], vt = v[i], pt = pr[i];
        float m = mask[i] ? 1.f : 0.f;
        float du = ut - up, dv = vt - vp, dp = pt - pv;
        s[0] = m * du * du; s[1] = m * dv * dv; s[2] = m * dp * dp;
        s[3] = du * du;     s[4] = dv * dv;     s[5] = dp * dp;
        s[6] = f_u * f_u;   s[7] = f_v * f_v;   s[8] = m;
    }
    int lane = threadIdx.x & 63, wid = threadIdx.x >> 6;
    __shared__ float red[4][9];
    #pragma unroll
    for (int k = 0; k < 9; ++k) {
        float xv = s[k];
        #pragma unroll
        for (int off = 32; off; off >>= 1) xv += __shfl_down(xv, off, 64);
        s[k] = xv;
    }
    if (lane == 0) {
        #pragma unroll
        for (int k = 0; k < 9; ++k) red[wid][k] = s[k];
    }
    __syncthreads();
    if (threadIdx.x == 0) {
        #pragma unroll
        for (int k = 0; k < 9; ++k)
            partials[blockIdx.x * 9 + k] = red[0][k] + red[1][k] + red[2][k] + red[3][k];
    }
}

__global__ void loss_final(const float* __restrict__ partials, float* __restrict__ out)
{
    int lane = threadIdx.x;
    float sums[9];
    #pragma unroll
    for (int k = 0; k < 9; ++k) {
        float xv = (lane < 32) ? partials[lane * 9 + k] : 0.f;
        #pragma unroll
        for (int off = 32; off; off >>= 1) xv += __shfl_down(xv, off, 64);
        sums[k] = xv;
    }
    if (lane == 0) {
        float ms = fmaxf(sums[8], 1.0f);
        float inv_n = 1.0f / (float)NPTS;
        float u_bc = sums[0] / ms, v_bc = sums[1] / ms, p_bc = sums[2] / ms;
        float u_tr = sums[3] * inv_n, v_tr = sums[4] * inv_n, p_tr = sums[5] * inv_n;
        float rans = sums[6] * inv_n + sums[7] * inv_n;
        out[0] = u_bc + v_bc + rans;
        out[1] = p_bc + rans;
        out[2] = u_tr;
        out[3] = v_tr;
        out[4] = p_tr;
        out[5] = rans;
    }
}

extern "C" void kernel_launch(void* const* d_in, const int* in_sizes, int n_in,
                              void* d_out, int out_size, void* d_ws, size_t ws_size,
                              hipStream_t stream)
{
    (void)in_sizes; (void)n_in; (void)out_size; (void)ws_size;
    const float* x    = (const float*)d_in[0];
    const float* y    = (const float*)d_in[1];
    const float* u    = (const float*)d_in[2];
    const float* v    = (const float*)d_in[3];
    const float* pr   = (const float*)d_in[4];
    const int*   mask = (const int*)d_in[5];
    const float* psi_W0 = (const float*)d_in[6];
    const float* psi_b0 = (const float*)d_in[7];
    const float* psi_Wm = (const float*)d_in[8];
    const float* psi_bm = (const float*)d_in[9];
    const float* psi_Wl = (const float*)d_in[10];
    const float* psi_bl = (const float*)d_in[11];
    const float* p_W0 = (const float*)d_in[12];
    const float* p_b0 = (const float*)d_in[13];
    const float* p_Wm = (const float*)d_in[14];
    const float* p_bm = (const float*)d_in[15];
    const float* p_Wl = (const float*)d_in[16];
    const float* p_bl = (const float*)d_in[17];

    float*  P        = (float*)d_ws;                 // NPTS*16
    float*  partials = P + (size_t)NPTS * 16;        // 512
    ushort* Wfh      = (ushort*)(partials + 512);    // 18*65536
    ushort* Wfl      = Wfh + (size_t)18 * 65536;

    wprep<<<288, 256, 0, stream>>>(psi_Wm, p_Wm, Wfh, Wfl);

    // psi net: 10 comps, dots over comps 1..9 -> P slots 0..8
    fused_net<10, 1, 9, 0, false><<<NPTS / 16, 512, 10 * 16384, stream>>>(
        x, y, psi_W0, psi_b0, Wfh, Wfl, psi_bm, psi_Wl, psi_bl, P);

    // p net: 3 comps, dots over comps 0..2 -> P slots 9..11 (+bl on value)
    fused_net<3, 0, 3, 9, true><<<NPTS / 16, 512, 3 * 16384, stream>>>(
        x, y, p_W0, p_b0, Wfh + (size_t)9 * 65536, Wfl + (size_t)9 * 65536,
        p_bm, p_Wl, p_bl, P);

    loss_partials<<<NPTS / 256, 256, 0, stream>>>(P, u, v, pr, mask, partials);
    loss_final<<<1, 64, 0, stream>>>(partials, (float*)d_out);
}

// Round 7
// 497.772 us; speedup vs baseline: 4.6052x; 1.4216x over previous
//
#include <hip/hip_runtime.h>
#include <hip/hip_bf16.h>
#include <math.h>

#define HIDDEN 256
#define NPTS 8192
#define NMID_L 9
#define NU_C 0.01f

typedef __attribute__((ext_vector_type(8))) short bf16x8;
typedef __attribute__((ext_vector_type(4))) float floatx4;

// ---------- bf16 helpers ----------
__device__ __forceinline__ ushort f2b(float a) {
    unsigned x = __float_as_uint(a);
    return (ushort)((x + 0x7fffu + ((x >> 16) & 1u)) >> 16);
}
__device__ __forceinline__ float b2f(ushort u) {
    return __uint_as_float(((unsigned)u) << 16);
}
__device__ __forceinline__ void split2(float a, ushort& hi, ushort& lo) {
    ushort h = f2b(a);
    lo = f2b(a - b2f(h));
    hi = h;
}

// softplus100 value + first three derivatives.
// sp(t) = max(t,0) + log1p(e^{-|t|});  log1p(e) = -log(1/(1+e)) = -log(r).
__device__ __forceinline__ void act_derivs(float z, float& h, float& s1, float& s2, float& s3)
{
    float t = 100.0f * z;
    float at = fabsf(t);
    float e = __expf(-at);
    float r = __builtin_amdgcn_rcpf(1.0f + e);   // 1/(1+e^{-|t|})
    float a_ = e * r;                             // e^{-|t|}/(1+e^{-|t|})
    bool pos = (t >= 0.0f);
    float s   = pos ? r  : a_;                    // sigmoid(t), good rel. accuracy
    float oms = pos ? a_ : r;                     // 1 - sigmoid(t)
    float sp = fmaxf(t, 0.0f) - __logf(r);
    h  = 0.01f * sp;
    s1 = s;
    s2 = 100.0f * s * oms;
    s3 = s2 * (100.0f - 200.0f * s);
}

// ---------- weight prep: W[k][n] -> B-fragment layout, split hi/lo ----------
// Granule index: (((l*8 + w)*2 + tt)*8 + ch)*64 + ks*16 + col  holds
// (n = w*32 + tt*16 + col, k = ch*32 + ks*8 + e), e = 0..7.
__global__ __launch_bounds__(256) void wprep(const float* __restrict__ psi_Wm,
                                             const float* __restrict__ p_Wm,
                                             ushort* __restrict__ Wfh, ushort* __restrict__ Wfl)
{
    int bid = blockIdx.x;
    int l = bid >> 4;            // 0..17
    int tile = bid & 15;
    int tk = (tile >> 2) * 64;
    int tn = (tile & 3) * 64;
    const float* W = (l < 9) ? (psi_Wm + (size_t)l * 65536)
                             : (p_Wm + (size_t)(l - 9) * 65536);
    __shared__ float tileS[64][65];
    int t = threadIdx.x;
    #pragma unroll
    for (int i = 0; i < 16; ++i) {
        int r = i * 4 + (t >> 6);
        int c = t & 63;
        tileS[r][c] = W[(size_t)(tk + r) * HIDDEN + tn + c];
    }
    __syncthreads();
    bf16x8* oh = (bf16x8*)Wfh;
    bf16x8* ol = (bf16x8*)Wfl;
    #pragma unroll
    for (int i = 0; i < 2; ++i) {
        int g = i * 256 + t;          // 0..511 granules of this 64x64 tile
        int n_loc = g >> 3;
        int kg = g & 7;
        int n = tn + n_loc;
        int k0 = tk + kg * 8;
        int w = n >> 5, tt = (n >> 4) & 1, col = n & 15;
        int ch = k0 >> 5, ks = (k0 >> 3) & 3;
        size_t fidx = ((((size_t)l * 8 + w) * 2 + tt) * 8 + ch) * 64 + ks * 16 + col;
        bf16x8 vh, vl;
        #pragma unroll
        for (int e = 0; e < 8; ++e) {
            ushort hh, ll;
            split2(tileS[kg * 8 + e][n_loc], hh, ll);
            vh[e] = (short)hh;
            vl[e] = (short)ll;
        }
        oh[fidx] = vh;
        ol[fidx] = vl;
    }
}

// ---------- fused whole-net kernel ----------
// 512 threads = 8 waves; block owns 16 points. Full jet state lives in LDS:
// region (c, ch) = 2 KB at smem + (c*8+ch)*2048; hi frag granules [0,1024),
// lo [1024,2048). A-frag: lane&15 = point, lane>>4 = k-granule.
// Wave w produces output cols [32w,32w+32) = exactly state chunk w -> wave-private
// transpose bounce. Bounce scratch uses a swizzled f32 layout:
//   value (p, kk) at byte  p*128 + (((kk>>2) + p)&7)*16 + (kk&3)*4
// -> scatter writes 2-way (free), readback b128 at the 8-words/bank minimum.
template<int C, int DF, int DN, int PB, bool ADDBL>
__global__ __launch_bounds__(512, 2) void fused_net(
    const float* __restrict__ x, const float* __restrict__ y,
    const float* __restrict__ W0, const float* __restrict__ b0,
    const ushort* __restrict__ Wfh, const ushort* __restrict__ Wfl,
    const float* __restrict__ bm,
    const float* __restrict__ Wl, const float* __restrict__ bl,
    float* __restrict__ P)
{
    extern __shared__ char smem[];
    const int t = threadIdx.x;
    const int lane = t & 63;
    const int wv = t >> 6;
    const int p0 = blockIdx.x * 16;

    // ---- layer 0: jet init directly into state (wave w fills chunk w) ----
    {
        float xx = x[p0 + (lane & 15)];
        float yy = y[p0 + (lane & 15)];
        bf16x8 vh[C], vl[C];
        #pragma unroll
        for (int e = 0; e < 8; ++e) {
            int j = wv * 32 + ((lane >> 4) << 3) + e;
            float ax = W0[j];
            float ay = W0[HIDDEN + j];
            float a = xx * ax + yy * ay + b0[j];
            float h, s1, s2, s3;
            act_derivs(a, h, s1, s2, s3);
            float vals[C];
            vals[0] = h; vals[1] = s1 * ax; vals[2] = s1 * ay;
            if constexpr (C == 10) {
                vals[3] = s2 * ax * ax;
                vals[4] = s2 * ax * ay;
                vals[5] = s2 * ay * ay;
                vals[6] = s3 * ax * ax * ax;
                vals[7] = s3 * ax * ax * ay;
                vals[8] = s3 * ax * ay * ay;
                vals[9] = s3 * ay * ay * ay;
            }
            #pragma unroll
            for (int c = 0; c < C; ++c) {
                ushort hh, ll;
                split2(vals[c], hh, ll);
                vh[c][e] = (short)hh;
                vl[c][e] = (short)ll;
            }
        }
        #pragma unroll
        for (int c = 0; c < C; ++c) {
            char* R = smem + (c * 8 + wv) * 2048;
            *(bf16x8*)(R + lane * 16) = vh[c];
            *(bf16x8*)(R + 1024 + lane * 16) = vl[c];
        }
    }
    __syncthreads();

    const bf16x8* WfhV = (const bf16x8*)Wfh;
    const bf16x8* WflV = (const bf16x8*)Wfl;

    // ---- 9 hidden layers ----
    for (int l = 0; l < NMID_L; ++l) {
        floatx4 acc[C][2];
        #pragma unroll
        for (int c = 0; c < C; ++c) {
            acc[c][0] = (floatx4){0.f, 0.f, 0.f, 0.f};
            acc[c][1] = (floatx4){0.f, 0.f, 0.f, 0.f};
        }
        const size_t wbase = ((size_t)l * 8 + wv) * 1024;   // granules
        for (int ch = 0; ch < 8; ++ch) {
            bf16x8 bh[2], blo[2];
            #pragma unroll
            for (int tt = 0; tt < 2; ++tt) {
                size_t bi = wbase + ((size_t)tt * 8 + ch) * 64 + lane;
                bh[tt] = WfhV[bi];
                blo[tt] = WflV[bi];
            }
            #pragma unroll
            for (int c = 0; c < C; ++c) {
                const char* rb = smem + (c * 8 + ch) * 2048 + lane * 16;
                bf16x8 ah = *(const bf16x8*)rb;
                bf16x8 al = *(const bf16x8*)(rb + 1024);
                #pragma unroll
                for (int tt = 0; tt < 2; ++tt) {
                    acc[c][tt] = __builtin_amdgcn_mfma_f32_16x16x32_bf16(ah, bh[tt], acc[c][tt], 0, 0, 0);
                    acc[c][tt] = __builtin_amdgcn_mfma_f32_16x16x32_bf16(ah, blo[tt], acc[c][tt], 0, 0, 0);
                    acc[c][tt] = __builtin_amdgcn_mfma_f32_16x16x32_bf16(al, bh[tt], acc[c][tt], 0, 0, 0);
                }
            }
        }
        __syncthreads();   // all waves done reading state for this layer

        // epilogue: bias + activation derivatives (thread-local)
        float bb[2];
        bb[0] = bm[l * 256 + wv * 32 + (lane & 15)];
        bb[1] = bm[l * 256 + wv * 32 + 16 + (lane & 15)];
        float hv[2][4], s1v[2][4], s2v[2][4], s3v[2][4];
        #pragma unroll
        for (int tt = 0; tt < 2; ++tt)
        #pragma unroll
        for (int r = 0; r < 4; ++r) {
            float z = acc[0][tt][r] + bb[tt];
            act_derivs(z, hv[tt][r], s1v[tt][r], s2v[tt][r], s3v[tt][r]);
        }

        // phase 1: chain rule + swizzled f32 scatter, ALL comps (batched)
        #pragma unroll
        for (int c = 0; c < C; ++c) {
            float ov[2][4];
            #pragma unroll
            for (int tt = 0; tt < 2; ++tt)
            #pragma unroll
            for (int r = 0; r < 4; ++r) {
                float s1 = s1v[tt][r], s2 = s2v[tt][r], s3 = s3v[tt][r];
                float ax = acc[1][tt][r], ay = acc[2][tt][r];
                float val;
                if (c == 0) val = hv[tt][r];
                else if (c == 1) val = s1 * ax;
                else if (c == 2) val = s1 * ay;
                else if constexpr (C == 10) {
                    float axx = acc[3][tt][r], axy = acc[4][tt][r], ayy = acc[5][tt][r];
                    float axxx = acc[6][tt][r], axxy = acc[7][tt][r];
                    float axyy = acc[8][tt][r], ayyy = acc[9][tt][r];
                    if (c == 3) val = s2 * ax * ax + s1 * axx;
                    else if (c == 4) val = s2 * ax * ay + s1 * axy;
                    else if (c == 5) val = s2 * ay * ay + s1 * ayy;
                    else if (c == 6) val = s3 * ax * ax * ax + 3.f * s2 * ax * axx + s1 * axxx;
                    else if (c == 7) val = s3 * ax * ax * ay + s2 * (2.f * ax * axy + ay * axx) + s1 * axxy;
                    else if (c == 8) val = s3 * ax * ay * ay + s2 * (2.f * ay * axy + ax * ayy) + s1 * axyy;
                    else val = s3 * ay * ay * ay + 3.f * s2 * ay * ayy + s1 * ayyy;
                } else val = 0.f;
                ov[tt][r] = val;
            }
            char* R = smem + (c * 8 + wv) * 2048;
            #pragma unroll
            for (int tt = 0; tt < 2; ++tt)
            #pragma unroll
            for (int r = 0; r < 4; ++r) {
                int p = ((lane >> 4) << 2) + r;
                int kk = tt * 16 + (lane & 15);
                int gsw = ((kk >> 2) + p) & 7;
                *(float*)(R + p * 128 + gsw * 16 + (kk & 3) * 4) = ov[tt][r];
            }
        }

        // phase 2: readback (one lgkm drain for all scatters) + split + final store
        #pragma unroll
        for (int c = 0; c < C; ++c) {
            char* R = smem + (c * 8 + wv) * 2048;
            int p = lane & 15, ks = lane >> 4;
            floatx4 f0 = *(const floatx4*)(R + p * 128 + (((ks * 2 + 0) + p) & 7) * 16);
            floatx4 f1 = *(const floatx4*)(R + p * 128 + (((ks * 2 + 1) + p) & 7) * 16);
            bf16x8 nh, nl;
            #pragma unroll
            for (int e = 0; e < 4; ++e) {
                ushort hh, ll;
                split2(f0[e], hh, ll);
                nh[e] = (short)hh; nl[e] = (short)ll;
            }
            #pragma unroll
            for (int e = 0; e < 4; ++e) {
                ushort hh, ll;
                split2(f1[e], hh, ll);
                nh[4 + e] = (short)hh; nl[4 + e] = (short)ll;
            }
            *(bf16x8*)(R + lane * 16) = nh;
            *(bf16x8*)(R + 1024 + lane * 16) = nl;
        }
        __syncthreads();   // state fully updated for next layer
    }

    // ---- final linear dots ----
    {
        float4 w0 = ((const float4*)Wl)[wv * 8 + (lane >> 4) * 2];
        float4 w1 = ((const float4*)Wl)[wv * 8 + (lane >> 4) * 2 + 1];
        float part[DN];
        #pragma unroll
        for (int i = 0; i < DN; ++i) {
            int c = DF + i;
            const char* rb = smem + (c * 8 + wv) * 2048 + lane * 16;
            bf16x8 vh = *(const bf16x8*)rb;
            bf16x8 vl = *(const bf16x8*)(rb + 1024);
            float s = 0.f;
            #pragma unroll
            for (int e = 0; e < 4; ++e)
                s += (b2f((ushort)vh[e]) + b2f((ushort)vl[e])) * (&w0.x)[e];
            #pragma unroll
            for (int e = 0; e < 4; ++e)
                s += (b2f((ushort)vh[4 + e]) + b2f((ushort)vl[4 + e])) * (&w1.x)[e];
            s += __shfl_xor(s, 16, 64);
            s += __shfl_xor(s, 32, 64);
            part[i] = s;
        }
        __syncthreads();   // all state reads done before scratch overwrite (c0 region)
        if (lane < 16) {
            float* sc = (float*)(smem + wv * 2048);
            #pragma unroll
            for (int i = 0; i < DN; ++i) sc[i * 16 + lane] = part[i];
        }
        __syncthreads();
        if (t < 16 * DN) {
            int p = t & 15, i = t >> 4;
            float s = 0.f;
            #pragma unroll
            for (int w = 0; w < 8; ++w)
                s += ((const float*)(smem + w * 2048))[i * 16 + p];
            if (ADDBL && i == 0) s += bl[0];
            P[(size_t)(p0 + p) * 16 + PB + i] = s;
        }
    }
}

// ---------- loss ----------
__global__ __launch_bounds__(256) void loss_partials(
    const float* __restrict__ P, const float* __restrict__ u,
    const float* __restrict__ v, const float* __restrict__ pr,
    const int* __restrict__ mask, float* __restrict__ partials)
{
    int i = blockIdx.x * 256 + threadIdx.x;
    float s[9];
    #pragma unroll
    for (int k = 0; k < 9; ++k) s[k] = 0.f;
    if (i < NPTS) {
        const float* Pi = P + (size_t)i * 16;
        float psix = Pi[0], psiy = Pi[1], psixx = Pi[2], psixy = Pi[3], psiyy = Pi[4];
        float psixxx = Pi[5], psixxy = Pi[6], psixyy = Pi[7], psiyyy = Pi[8];
        float pv = Pi[9], ppx = Pi[10], ppy = Pi[11];
        float up = psiy, vp = -psix;
        float u_x = psixy, u_y = psiyy, v_x = -psixx, v_y = -psixy;
        float u_xx = psixxy, u_yy = psiyyy, v_xx = -psixxx, v_yy = -psixyy;
        float f_u = 2.f * up * u_x + up * v_y + vp * u_y + ppx - NU_C * (u_xx + u_yy);
        float f_v = 2.f * vp * v_y + up * v_x + vp * u_x + ppy - NU_C * (v_xx + v_yy);
        float ut = u[i], vt = v[i], pt = pr[i];
        float m = mask[i] ? 1.f : 0.f;
        float du = ut - up, dv = vt - vp, dp = pt - pv;
        s[0] = m * du * du; s[1] = m * dv * dv; s[2] = m * dp * dp;
        s[3] = du * du;     s[4] = dv * dv;     s[5] = dp * dp;
        s[6] = f_u * f_u;   s[7] = f_v * f_v;   s[8] = m;
    }
    int lane = threadIdx.x & 63, wid = threadIdx.x >> 6;
    __shared__ float red[4][9];
    #pragma unroll
    for (int k = 0; k < 9; ++k) {
        float xv = s[k];
        #pragma unroll
        for (int off = 32; off; off >>= 1) xv += __shfl_down(xv, off, 64);
        s[k] = xv;
    }
    if (lane == 0) {
        #pragma unroll
        for (int k = 0; k < 9; ++k) red[wid][k] = s[k];
    }
    __syncthreads();
    if (threadIdx.x == 0) {
        #pragma unroll
        for (int k = 0; k < 9; ++k)
            partials[blockIdx.x * 9 + k] = red[0][k] + red[1][k] + red[2][k] + red[3][k];
    }
}

__global__ void loss_final(const float* __restrict__ partials, float* __restrict__ out)
{
    int lane = threadIdx.x;
    float sums[9];
    #pragma unroll
    for (int k = 0; k < 9; ++k) {
        float xv = (lane < 32) ? partials[lane * 9 + k] : 0.f;
        #pragma unroll
        for (int off = 32; off; off >>= 1) xv += __shfl_down(xv, off, 64);
        sums[k] = xv;
    }
    if (lane == 0) {
        float ms = fmaxf(sums[8], 1.0f);
        float inv_n = 1.0f / (float)NPTS;
        float u_bc = sums[0] / ms, v_bc = sums[1] / ms, p_bc = sums[2] / ms;
        float u_tr = sums[3] * inv_n, v_tr = sums[4] * inv_n, p_tr = sums[5] * inv_n;
        float rans = sums[6] * inv_n + sums[7] * inv_n;
        out[0] = u_bc + v_bc + rans;
        out[1] = p_bc + rans;
        out[2] = u_tr;
        out[3] = v_tr;
        out[4] = p_tr;
        out[5] = rans;
    }
}

extern "C" void kernel_launch(void* const* d_in, const int* in_sizes, int n_in,
                              void* d_out, int out_size, void* d_ws, size_t ws_size,
                              hipStream_t stream)
{
    (void)in_sizes; (void)n_in; (void)out_size; (void)ws_size;
    const float* x    = (const float*)d_in[0];
    const float* y    = (const float*)d_in[1];
    const float* u    = (const float*)d_in[2];
    const float* v    = (const float*)d_in[3];
    const float* pr   = (const float*)d_in[4];
    const int*   mask = (const int*)d_in[5];
    const float* psi_W0 = (const float*)d_in[6];
    const float* psi_b0 = (const float*)d_in[7];
    const float* psi_Wm = (const float*)d_in[8];
    const float* psi_bm = (const float*)d_in[9];
    const float* psi_Wl = (const float*)d_in[10];
    const float* psi_bl = (const float*)d_in[11];
    const float* p_W0 = (const float*)d_in[12];
    const float* p_b0 = (const float*)d_in[13];
    const float* p_Wm = (const float*)d_in[14];
    const float* p_bm = (const float*)d_in[15];
    const float* p_Wl = (const float*)d_in[16];
    const float* p_bl = (const float*)d_in[17];

    float*  P        = (float*)d_ws;                 // NPTS*16
    float*  partials = P + (size_t)NPTS * 16;        // 512
    ushort* Wfh      = (ushort*)(partials + 512);    // 18*65536
    ushort* Wfl      = Wfh + (size_t)18 * 65536;

    wprep<<<288, 256, 0, stream>>>(psi_Wm, p_Wm, Wfh, Wfl);

    // psi net: 10 comps, dots over comps 1..9 -> P slots 0..8
    fused_net<10, 1, 9, 0, false><<<NPTS / 16, 512, 10 * 16384, stream>>>(
        x, y, psi_W0, psi_b0, Wfh, Wfl, psi_bm, psi_Wl, psi_bl, P);

    // p net: 3 comps, dots over comps 0..2 -> P slots 9..11 (+bl on value)
    fused_net<3, 0, 3, 9, true><<<NPTS / 16, 512, 3 * 16384, stream>>>(
        x, y, p_W0, p_b0, Wfh + (size_t)9 * 65536, Wfl + (size_t)9 * 65536,
        p_bm, p_Wl, p_bl, P);

    loss_partials<<<NPTS / 256, 256, 0, stream>>>(P, u, v, pr, mask, partials);
    loss_final<<<1, 64, 0, stream>>>(partials, (float*)d_out);
}

// Round 8
// 471.534 us; speedup vs baseline: 4.8615x; 1.0556x over previous
//
#include <hip/hip_runtime.h>
#include <hip/hip_bf16.h>
#include <math.h>

#define HIDDEN 256
#define NPTS 8192
#define NMID_L 9
#define NU_C 0.01f

typedef __attribute__((ext_vector_type(8))) short bf16x8;
typedef __attribute__((ext_vector_type(4))) float floatx4;
typedef __attribute__((ext_vector_type(4))) unsigned uintx4;

// ---------- bf16 helpers ----------
__device__ __forceinline__ ushort f2b(float a) {
    unsigned x = __float_as_uint(a);
    return (ushort)((x + 0x7fffu + ((x >> 16) & 1u)) >> 16);
}
__device__ __forceinline__ float b2f(ushort u) {
    return __uint_as_float(((unsigned)u) << 16);
}
__device__ __forceinline__ void split2(float a, ushort& hi, ushort& lo) {
    ushort h = f2b(a);
    lo = f2b(a - b2f(h));
    hi = h;
}
// packed state word: (hi<<16) | lo, hi/lo bf16, lo = rnd(a - hi) exact-residual
__device__ __forceinline__ unsigned packsplit(float a) {
    ushort h = f2b(a);
    ushort l = f2b(a - b2f(h));
    return ((unsigned)h << 16) | (unsigned)l;
}

// softplus100 value + first three derivatives.
__device__ __forceinline__ void act_derivs(float z, float& h, float& s1, float& s2, float& s3)
{
    float t = 100.0f * z;
    float at = fabsf(t);
    float e = __expf(-at);
    float r = __builtin_amdgcn_rcpf(1.0f + e);   // 1/(1+e^{-|t|})
    float a_ = e * r;
    bool pos = (t >= 0.0f);
    float s   = pos ? r  : a_;
    float oms = pos ? a_ : r;
    float sp = fmaxf(t, 0.0f) - __logf(r);
    h  = 0.01f * sp;
    s1 = s;
    s2 = 100.0f * s * oms;
    s3 = s2 * (100.0f - 200.0f * s);
}

// ---------- weight prep: W[k][n] -> B-fragment layout, split hi/lo ----------
__global__ __launch_bounds__(256) void wprep(const float* __restrict__ psi_Wm,
                                             const float* __restrict__ p_Wm,
                                             ushort* __restrict__ Wfh, ushort* __restrict__ Wfl)
{
    int bid = blockIdx.x;
    int l = bid >> 4;            // 0..17
    int tile = bid & 15;
    int tk = (tile >> 2) * 64;
    int tn = (tile & 3) * 64;
    const float* W = (l < 9) ? (psi_Wm + (size_t)l * 65536)
                             : (p_Wm + (size_t)(l - 9) * 65536);
    __shared__ float tileS[64][65];
    int t = threadIdx.x;
    #pragma unroll
    for (int i = 0; i < 16; ++i) {
        int r = i * 4 + (t >> 6);
        int c = t & 63;
        tileS[r][c] = W[(size_t)(tk + r) * HIDDEN + tn + c];
    }
    __syncthreads();
    bf16x8* oh = (bf16x8*)Wfh;
    bf16x8* ol = (bf16x8*)Wfl;
    #pragma unroll
    for (int i = 0; i < 2; ++i) {
        int g = i * 256 + t;
        int n_loc = g >> 3;
        int kg = g & 7;
        int n = tn + n_loc;
        int k0 = tk + kg * 8;
        int w = n >> 5, tt = (n >> 4) & 1, col = n & 15;
        int ch = k0 >> 5, ks = (k0 >> 3) & 3;
        size_t fidx = ((((size_t)l * 8 + w) * 2 + tt) * 8 + ch) * 64 + ks * 16 + col;
        bf16x8 vh, vl;
        #pragma unroll
        for (int e = 0; e < 8; ++e) {
            ushort hh, ll;
            split2(tileS[kg * 8 + e][n_loc], hh, ll);
            vh[e] = (short)hh;
            vl[e] = (short)ll;
        }
        oh[fidx] = vh;
        ol[fidx] = vl;
    }
}

// ---------- fused whole-net kernel (packed-u32 state, scatter-only epilogue) ----
// 512 threads = 8 waves; block owns 16 points. State region (c,ch) = 2 KB at
// smem + (c*8+ch)*2048, holding u32-packed (hi|lo) values in the swizzled layout:
//   value (p, kk) at byte  p*128 + (((kk>>2) + p)&7)*16 + (kk&3)*4
// MFMA phase reads 2x b128 per (c,ch) and unpacks hi/lo frags via v_perm
// (hidden under MFMA issue). Epilogue = chain rule + packsplit + 8 ds_write_b32
// per comp (wave-private region) -- no readback/restore phase.
template<int C, int DF, int DN, int PB, bool ADDBL>
__global__ __launch_bounds__(512, 2) void fused_net(
    const float* __restrict__ x, const float* __restrict__ y,
    const float* __restrict__ W0, const float* __restrict__ b0,
    const ushort* __restrict__ Wfh, const ushort* __restrict__ Wfl,
    const float* __restrict__ bm,
    const float* __restrict__ Wl, const float* __restrict__ bl,
    float* __restrict__ P)
{
    extern __shared__ char smem[];
    const int t = threadIdx.x;
    const int lane = t & 63;
    const int wv = t >> 6;
    const int p0 = blockIdx.x * 16;
    const int lp = lane & 15;       // point-in-frag / row
    const int kg = lane >> 4;       // k-granule

    // ---- layer 0: jet init straight into packed-swizzled state ----
    {
        float xx = x[p0 + lp];
        float yy = y[p0 + lp];
        unsigned pk[C][8];
        #pragma unroll
        for (int e = 0; e < 8; ++e) {
            int j = wv * 32 + kg * 8 + e;
            float ax = W0[j];
            float ay = W0[HIDDEN + j];
            float a = xx * ax + yy * ay + b0[j];
            float h, s1, s2, s3;
            act_derivs(a, h, s1, s2, s3);
            float vals[C];
            vals[0] = h; vals[1] = s1 * ax; vals[2] = s1 * ay;
            if constexpr (C == 10) {
                vals[3] = s2 * ax * ax;
                vals[4] = s2 * ax * ay;
                vals[5] = s2 * ay * ay;
                vals[6] = s3 * ax * ax * ax;
                vals[7] = s3 * ax * ax * ay;
                vals[8] = s3 * ax * ay * ay;
                vals[9] = s3 * ay * ay * ay;
            }
            #pragma unroll
            for (int c = 0; c < C; ++c) pk[c][e] = packsplit(vals[c]);
        }
        #pragma unroll
        for (int c = 0; c < C; ++c) {
            char* R = smem + (c * 8 + wv) * 2048 + lp * 128;
            uintx4 q0 = {pk[c][0], pk[c][1], pk[c][2], pk[c][3]};
            uintx4 q1 = {pk[c][4], pk[c][5], pk[c][6], pk[c][7]};
            *(uintx4*)(R + (((kg * 2 + 0) + lp) & 7) * 16) = q0;
            *(uintx4*)(R + (((kg * 2 + 1) + lp) & 7) * 16) = q1;
        }
    }
    __syncthreads();

    const bf16x8* WfhV = (const bf16x8*)Wfh;
    const bf16x8* WflV = (const bf16x8*)Wfl;

    // ---- 9 hidden layers ----
    for (int l = 0; l < NMID_L; ++l) {
        floatx4 acc[C][2];
        #pragma unroll
        for (int c = 0; c < C; ++c) {
            acc[c][0] = (floatx4){0.f, 0.f, 0.f, 0.f};
            acc[c][1] = (floatx4){0.f, 0.f, 0.f, 0.f};
        }
        const size_t wbase = ((size_t)l * 8 + wv) * 1024;
        #pragma unroll
        for (int ch = 0; ch < 8; ++ch) {
            bf16x8 bh[2], blo[2];
            #pragma unroll
            for (int tt = 0; tt < 2; ++tt) {
                size_t bi = wbase + ((size_t)tt * 8 + ch) * 64 + lane;
                bh[tt] = WfhV[bi];
                blo[tt] = WflV[bi];
            }
            const int sw0 = (((kg * 2 + 0) + lp) & 7) * 16;
            const int sw1 = (((kg * 2 + 1) + lp) & 7) * 16;
            #pragma unroll
            for (int c = 0; c < C; ++c) {
                const char* R = smem + (c * 8 + ch) * 2048 + lp * 128;
                uintx4 u0 = *(const uintx4*)(R + sw0);
                uintx4 u1 = *(const uintx4*)(R + sw1);
                uintx4 hu, lu;
                hu[0] = __builtin_amdgcn_perm(u0[1], u0[0], 0x07060302u);
                hu[1] = __builtin_amdgcn_perm(u0[3], u0[2], 0x07060302u);
                hu[2] = __builtin_amdgcn_perm(u1[1], u1[0], 0x07060302u);
                hu[3] = __builtin_amdgcn_perm(u1[3], u1[2], 0x07060302u);
                lu[0] = __builtin_amdgcn_perm(u0[1], u0[0], 0x05040100u);
                lu[1] = __builtin_amdgcn_perm(u0[3], u0[2], 0x05040100u);
                lu[2] = __builtin_amdgcn_perm(u1[1], u1[0], 0x05040100u);
                lu[3] = __builtin_amdgcn_perm(u1[3], u1[2], 0x05040100u);
                bf16x8 ah = __builtin_bit_cast(bf16x8, hu);
                bf16x8 al = __builtin_bit_cast(bf16x8, lu);
                #pragma unroll
                for (int tt = 0; tt < 2; ++tt) {
                    acc[c][tt] = __builtin_amdgcn_mfma_f32_16x16x32_bf16(ah, bh[tt], acc[c][tt], 0, 0, 0);
                    acc[c][tt] = __builtin_amdgcn_mfma_f32_16x16x32_bf16(ah, blo[tt], acc[c][tt], 0, 0, 0);
                    acc[c][tt] = __builtin_amdgcn_mfma_f32_16x16x32_bf16(al, bh[tt], acc[c][tt], 0, 0, 0);
                }
            }
        }
        __syncthreads();   // all waves done reading state for this layer

        // epilogue: bias + activation derivatives (thread-local)
        float bb[2];
        bb[0] = bm[l * 256 + wv * 32 + lp];
        bb[1] = bm[l * 256 + wv * 32 + 16 + lp];
        float hv[2][4], s1v[2][4], s2v[2][4], s3v[2][4];
        #pragma unroll
        for (int tt = 0; tt < 2; ++tt)
        #pragma unroll
        for (int r = 0; r < 4; ++r) {
            float z = acc[0][tt][r] + bb[tt];
            act_derivs(z, hv[tt][r], s1v[tt][r], s2v[tt][r], s3v[tt][r]);
        }

        // chain rule + packsplit + swizzled u32 scatter (wave-private region)
        #pragma unroll
        for (int c = 0; c < C; ++c) {
            char* R = smem + (c * 8 + wv) * 2048;
            #pragma unroll
            for (int tt = 0; tt < 2; ++tt)
            #pragma unroll
            for (int r = 0; r < 4; ++r) {
                float s1 = s1v[tt][r], s2 = s2v[tt][r], s3 = s3v[tt][r];
                float ax = acc[1][tt][r], ay = acc[2][tt][r];
                float val;
                if (c == 0) val = hv[tt][r];
                else if (c == 1) val = s1 * ax;
                else if (c == 2) val = s1 * ay;
                else if constexpr (C == 10) {
                    float axx = acc[3][tt][r], axy = acc[4][tt][r], ayy = acc[5][tt][r];
                    float axxx = acc[6][tt][r], axxy = acc[7][tt][r];
                    float axyy = acc[8][tt][r], ayyy = acc[9][tt][r];
                    if (c == 3) val = s2 * ax * ax + s1 * axx;
                    else if (c == 4) val = s2 * ax * ay + s1 * axy;
                    else if (c == 5) val = s2 * ay * ay + s1 * ayy;
                    else if (c == 6) val = s3 * ax * ax * ax + 3.f * s2 * ax * axx + s1 * axxx;
                    else if (c == 7) val = s3 * ax * ax * ay + s2 * (2.f * ax * axy + ay * axx) + s1 * axxy;
                    else if (c == 8) val = s3 * ax * ay * ay + s2 * (2.f * ay * axy + ax * ayy) + s1 * axyy;
                    else val = s3 * ay * ay * ay + 3.f * s2 * ay * ayy + s1 * ayyy;
                } else val = 0.f;
                int p = (kg << 2) + r;
                int kk = tt * 16 + lp;
                int sw = ((kk >> 2) + p) & 7;
                *(unsigned*)(R + p * 128 + sw * 16 + (kk & 3) * 4) = packsplit(val);
            }
        }
        __syncthreads();   // state fully updated for next layer
    }

    // ---- final linear dots ----
    {
        float4 w0 = ((const float4*)Wl)[wv * 8 + kg * 2];
        float4 w1 = ((const float4*)Wl)[wv * 8 + kg * 2 + 1];
        float part[DN];
        #pragma unroll
        for (int i = 0; i < DN; ++i) {
            int c = DF + i;
            const char* R = smem + (c * 8 + wv) * 2048 + lp * 128;
            uintx4 u0 = *(const uintx4*)(R + (((kg * 2 + 0) + lp) & 7) * 16);
            uintx4 u1 = *(const uintx4*)(R + (((kg * 2 + 1) + lp) & 7) * 16);
            float s = 0.f;
            #pragma unroll
            for (int e = 0; e < 4; ++e)
                s += (b2f((ushort)(u0[e] >> 16)) + b2f((ushort)(u0[e] & 0xffffu))) * (&w0.x)[e];
            #pragma unroll
            for (int e = 0; e < 4; ++e)
                s += (b2f((ushort)(u1[e] >> 16)) + b2f((ushort)(u1[e] & 0xffffu))) * (&w1.x)[e];
            s += __shfl_xor(s, 16, 64);
            s += __shfl_xor(s, 32, 64);
            part[i] = s;
        }
        __syncthreads();   // all state reads done before scratch overwrite
        if (lane < 16) {
            float* sc = (float*)(smem + wv * 2048);
            #pragma unroll
            for (int i = 0; i < DN; ++i) sc[i * 16 + lane] = part[i];
        }
        __syncthreads();
        if (t < 16 * DN) {
            int p = t & 15, i = t >> 4;
            float s = 0.f;
            #pragma unroll
            for (int w = 0; w < 8; ++w)
                s += ((const float*)(smem + w * 2048))[i * 16 + p];
            if (ADDBL && i == 0) s += bl[0];
            P[(size_t)(p0 + p) * 16 + PB + i] = s;
        }
    }
}

// ---------- loss ----------
__global__ __launch_bounds__(256) void loss_partials(
    const float* __restrict__ P, const float* __restrict__ u,
    const float* __restrict__ v, const float* __restrict__ pr,
    const int* __restrict__ mask, float* __restrict__ partials)
{
    int i = blockIdx.x * 256 + threadIdx.x;
    float s[9];
    #pragma unroll
    for (int k = 0; k < 9; ++k) s[k] = 0.f;
    if (i < NPTS) {
        const float* Pi = P + (size_t)i * 16;
        float psix = Pi[0], psiy = Pi[1], psixx = Pi[2], psixy = Pi[3], psiyy = Pi[4];
        float psixxx = Pi[5], psixxy = Pi[6], psixyy = Pi[7], psiyyy = Pi[8];
        float pv = Pi[9], ppx = Pi[10], ppy = Pi[11];
        float up = psiy, vp = -psix;
        float u_x = psixy, u_y = psiyy, v_x = -psixx, v_y = -psixy;
        float u_xx = psixxy, u_yy = psiyyy, v_xx = -psixxx, v_yy = -psixyy;
        float f_u = 2.f * up * u_x + up * v_y + vp * u_y + ppx - NU_C * (u_xx + u_yy);
        float f_v = 2.f * vp * v_y + up * v_x + vp * u_x + ppy - NU_C * (v_xx + v_yy);
        float ut = u[i], vt = v[i], pt = pr[i];
        float m = mask[i] ? 1.f : 0.f;
        float du = ut - up, dv = vt - vp, dp = pt - pv;
        s[0] = m * du * du; s[1] = m * dv * dv; s[2] = m * dp * dp;
        s[3] = du * du;     s[4] = dv * dv;     s[5] = dp * dp;
        s[6] = f_u * f_u;   s[7] = f_v * f_v;   s[8] = m;
    }
    int lane = threadIdx.x & 63, wid = threadIdx.x >> 6;
    __shared__ float red[4][9];
    #pragma unroll
    for (int k = 0; k < 9; ++k) {
        float xv = s[k];
        #pragma unroll
        for (int off = 32; off; off >>= 1) xv += __shfl_down(xv, off, 64);
        s[k] = xv;
    }
    if (lane == 0) {
        #pragma unroll
        for (int k = 0; k < 9; ++k) red[wid][k] = s[k];
    }
    __syncthreads();
    if (threadIdx.x == 0) {
        #pragma unroll
        for (int k = 0; k < 9; ++k)
            partials[blockIdx.x * 9 + k] = red[0][k] + red[1][k] + red[2][k] + red[3][k];
    }
}

__global__ void loss_final(const float* __restrict__ partials, float* __restrict__ out)
{
    int lane = threadIdx.x;
    float sums[9];
    #pragma unroll
    for (int k = 0; k < 9; ++k) {
        float xv = (lane < 32) ? partials[lane * 9 + k] : 0.f;
        #pragma unroll
        for (int off = 32; off; off >>= 1) xv += __shfl_down(xv, off, 64);
        sums[k] = xv;
    }
    if (lane == 0) {
        float ms = fmaxf(sums[8], 1.0f);
        float inv_n = 1.0f / (float)NPTS;
        float u_bc = sums[0] / ms, v_bc = sums[1] / ms, p_bc = sums[2] / ms;
        float u_tr = sums[3] * inv_n, v_tr = sums[4] * inv_n, p_tr = sums[5] * inv_n;
        float rans = sums[6] * inv_n + sums[7] * inv_n;
        out[0] = u_bc + v_bc + rans;
        out[1] = p_bc + rans;
        out[2] = u_tr;
        out[3] = v_tr;
        out[4] = p_tr;
        out[5] = rans;
    }
}

extern "C" void kernel_launch(void* const* d_in, const int* in_sizes, int n_in,
                              void* d_out, int out_size, void* d_ws, size_t ws_size,
                              hipStream_t stream)
{
    (void)in_sizes; (void)n_in; (void)out_size; (void)ws_size;
    const float* x    = (const float*)d_in[0];
    const float* y    = (const float*)d_in[1];
    const float* u    = (const float*)d_in[2];
    const float* v    = (const float*)d_in[3];
    const float* pr   = (const float*)d_in[4];
    const int*   mask = (const int*)d_in[5];
    const float* psi_W0 = (const float*)d_in[6];
    const float* psi_b0 = (const float*)d_in[7];
    const float* psi_Wm = (const float*)d_in[8];
    const float* psi_bm = (const float*)d_in[9];
    const float* psi_Wl = (const float*)d_in[10];
    const float* psi_bl = (const float*)d_in[11];
    const float* p_W0 = (const float*)d_in[12];
    const float* p_b0 = (const float*)d_in[13];
    const float* p_Wm = (const float*)d_in[14];
    const float* p_bm = (const float*)d_in[15];
    const float* p_Wl = (const float*)d_in[16];
    const float* p_bl = (const float*)d_in[17];

    float*  P        = (float*)d_ws;                 // NPTS*16
    float*  partials = P + (size_t)NPTS * 16;        // 512
    ushort* Wfh      = (ushort*)(partials + 512);    // 18*65536
    ushort* Wfl      = Wfh + (size_t)18 * 65536;

    wprep<<<288, 256, 0, stream>>>(psi_Wm, p_Wm, Wfh, Wfl);

    // psi net: 10 comps, dots over comps 1..9 -> P slots 0..8
    fused_net<10, 1, 9, 0, false><<<NPTS / 16, 512, 10 * 16384, stream>>>(
        x, y, psi_W0, psi_b0, Wfh, Wfl, psi_bm, psi_Wl, psi_bl, P);

    // p net: 3 comps, dots over comps 0..2 -> P slots 9..11 (+bl on value)
    fused_net<3, 0, 3, 9, true><<<NPTS / 16, 512, 3 * 16384, stream>>>(
        x, y, p_W0, p_b0, Wfh + (size_t)9 * 65536, Wfl + (size_t)9 * 65536,
        p_bm, p_Wl, p_bl, P);

    loss_partials<<<NPTS / 256, 256, 0, stream>>>(P, u, v, pr, mask, partials);
    loss_final<<<1, 64, 0, stream>>>(partials, (float*)d_out);
}

// Round 9
// 467.592 us; speedup vs baseline: 4.9025x; 1.0084x over previous
//
#include <hip/hip_runtime.h>
#include <hip/hip_bf16.h>
#include <math.h>

#define HIDDEN 256
#define NPTS 8192
#define NMID_L 9
#define NU_C 0.01f

typedef __attribute__((ext_vector_type(8))) short bf16x8;
typedef __attribute__((ext_vector_type(4))) float floatx4;
typedef __attribute__((ext_vector_type(4))) unsigned uintx4;

// ---------- bf16 helpers ----------
__device__ __forceinline__ ushort f2b(float a) {
    unsigned x = __float_as_uint(a);
    return (ushort)((x + 0x7fffu + ((x >> 16) & 1u)) >> 16);
}
__device__ __forceinline__ float b2f(ushort u) {
    return __uint_as_float(((unsigned)u) << 16);
}
__device__ __forceinline__ void split2(float a, ushort& hi, ushort& lo) {
    ushort h = f2b(a);
    lo = f2b(a - b2f(h));
    hi = h;
}
// packed state word: (hi<<16) | lo
__device__ __forceinline__ unsigned packsplit(float a) {
    ushort h = f2b(a);
    ushort l = f2b(a - b2f(h));
    return ((unsigned)h << 16) | (unsigned)l;
}

// k-permutation pi (must match between wprep A-frags and state B-frags):
// within a 32-k chunk, slot (kgg, e') holds kappa = 16*(kgg>>1) + 4*(e'>>1) + 2*(kgg&1) + (e'&1)
__device__ __forceinline__ int kappa_of(int kgg, int ep) {
    return 16 * (kgg >> 1) + 4 * (ep >> 1) + 2 * (kgg & 1) + (ep & 1);
}

// softplus100 value + first three derivatives.
__device__ __forceinline__ void act_derivs(float z, float& h, float& s1, float& s2, float& s3)
{
    float t = 100.0f * z;
    float at = fabsf(t);
    float e = __expf(-at);
    float r = __builtin_amdgcn_rcpf(1.0f + e);
    float a_ = e * r;
    bool pos = (t >= 0.0f);
    float s   = pos ? r  : a_;
    float oms = pos ? a_ : r;
    float sp = fmaxf(t, 0.0f) - __logf(r);
    h  = 0.01f * sp;
    s1 = s;
    s2 = 100.0f * s * oms;
    s3 = s2 * (100.0f - 200.0f * s);
}

// ---------- weight prep: W[k][n] -> A-fragment layout (W as MFMA A operand) ----
// Granule (l, wv, tt, ch), lane = m + 16*kgg: elem e' = W[ch*32 + kappa(kgg,e')][wv*32+tt*16+m]
__global__ __launch_bounds__(256) void wprep(const float* __restrict__ psi_Wm,
                                             const float* __restrict__ p_Wm,
                                             ushort* __restrict__ Wfh, ushort* __restrict__ Wfl)
{
    int bid = blockIdx.x;          // 18*8 = 144 blocks
    int l = bid >> 3, wv = bid & 7;
    const float* W = (l < 9) ? (psi_Wm + (size_t)l * 65536)
                             : (p_Wm + (size_t)(l - 9) * 65536);
    int t = threadIdx.x;
    int lane = t & 63;
    int m = lane & 15, kgg = lane >> 4;
    int grp = t >> 6;
    bf16x8* oh = (bf16x8*)Wfh;
    bf16x8* ol = (bf16x8*)Wfl;
    #pragma unroll
    for (int gi = 0; gi < 4; ++gi) {
        int gid = grp * 4 + gi;     // 0..15
        int tt = gid >> 3, ch = gid & 7;
        int n = wv * 32 + tt * 16 + m;
        bf16x8 vh, vl;
        #pragma unroll
        for (int ep = 0; ep < 8; ++ep) {
            int k = ch * 32 + kappa_of(kgg, ep);
            ushort hh, ll;
            split2(W[(size_t)k * HIDDEN + n], hh, ll);
            vh[ep] = (short)hh;
            vl[ep] = (short)ll;
        }
        size_t fidx = ((((size_t)l * 8 + wv) * 2 + tt) * 8 + ch) * 64 + lane;
        oh[fidx] = vh;
        ol[fidx] = vl;
    }
}

// ---------- fused whole-net kernel (operand-swapped: A = W, B = state) ----------
// 512 thr = 8 waves; block owns 16 points. State region (c,ch) = 2 KB at
// smem + (c*8+ch)*2048: packed-u32 B-frags, word (pt + 16*kgg)*8 + e'
// (value = state k-in-chunk kappa(kgg,e') for point pt). MFMA-phase reads are
// lane-LINEAR (lane*32B + {0,16}) -> conflict-free (r7-proven pattern); hi/lo
// unpacked via v_perm. D: col=pt (lane&15), row=output-unit (4*(lane>>4)+r per
// tile tt). Epilogue: chain rule + packsplit + 4 ds_write_b64 per comp straight
// into final layout (banks fully spread by pi) -- no bounce/readback.
template<int C, int DF, int DN, int PB, bool ADDBL>
__global__ __launch_bounds__(512, 2) void fused_net(
    const float* __restrict__ x, const float* __restrict__ y,
    const float* __restrict__ W0, const float* __restrict__ b0,
    const ushort* __restrict__ Wfh, const ushort* __restrict__ Wfl,
    const float* __restrict__ bm,
    const float* __restrict__ Wl, const float* __restrict__ bl,
    float* __restrict__ P)
{
    extern __shared__ char smem[];
    const int t = threadIdx.x;
    const int lane = t & 63;
    const int wv = t >> 6;
    const int p0 = blockIdx.x * 16;
    const int lp = lane & 15;       // point
    const int kg = lane >> 4;       // k-octet index

    // ---- layer 0: jet init straight into pi-packed state (wave wv -> chunk wv) ----
    {
        float xx = x[p0 + lp];
        float yy = y[p0 + lp];
        #pragma unroll
        for (int e = 0; e < 8; e += 2) {
            float vals2[C][2];
            #pragma unroll
            for (int ee = 0; ee < 2; ++ee) {
                int j = wv * 32 + kg * 8 + e + ee;
                float ax = W0[j];
                float ay = W0[HIDDEN + j];
                float a = xx * ax + yy * ay + b0[j];
                float h, s1, s2, s3;
                act_derivs(a, h, s1, s2, s3);
                vals2[0][ee] = h; vals2[1][ee] = s1 * ax; vals2[2][ee] = s1 * ay;
                if constexpr (C == 10) {
                    vals2[3][ee] = s2 * ax * ax;
                    vals2[4][ee] = s2 * ax * ay;
                    vals2[5][ee] = s2 * ay * ay;
                    vals2[6][ee] = s3 * ax * ax * ax;
                    vals2[7][ee] = s3 * ax * ax * ay;
                    vals2[8][ee] = s3 * ax * ay * ay;
                    vals2[9][ee] = s3 * ay * ay * ay;
                }
            }
            int kap = kg * 8 + e;                       // even
            int kgg = 2 * (kap >> 4) + ((kap >> 1) & 1);
            int ep  = 2 * ((kap >> 2) & 3);             // e' for kap, kap+1 -> ep, ep+1
            #pragma unroll
            for (int c = 0; c < C; ++c) {
                char* R = smem + (c * 8 + wv) * 2048;
                uint2 q;
                q.x = packsplit(vals2[c][0]);
                q.y = packsplit(vals2[c][1]);
                *(uint2*)(R + (lp + 16 * kgg) * 32 + ep * 4) = q;
            }
        }
    }
    __syncthreads();

    const bf16x8* WfhV = (const bf16x8*)Wfh;
    const bf16x8* WflV = (const bf16x8*)Wfl;

    // ---- 9 hidden layers ----
    for (int l = 0; l < NMID_L; ++l) {
        floatx4 acc[C][2];
        #pragma unroll
        for (int c = 0; c < C; ++c) {
            acc[c][0] = (floatx4){0.f, 0.f, 0.f, 0.f};
            acc[c][1] = (floatx4){0.f, 0.f, 0.f, 0.f};
        }
        const size_t wbase = ((size_t)l * 8 + wv) * 1024;
        #pragma unroll
        for (int ch = 0; ch < 8; ++ch) {
            bf16x8 wah[2], wal[2];          // A = weights (this wave's 2 tiles)
            #pragma unroll
            for (int tt = 0; tt < 2; ++tt) {
                size_t bi = wbase + ((size_t)tt * 8 + ch) * 64 + lane;
                wah[tt] = WfhV[bi];
                wal[tt] = WflV[bi];
            }
            #pragma unroll
            for (int c = 0; c < C; ++c) {
                const char* R = smem + (c * 8 + ch) * 2048 + lane * 32;   // LINEAR
                uintx4 u0 = *(const uintx4*)R;
                uintx4 u1 = *(const uintx4*)(R + 16);
                uintx4 hu, lu;
                hu[0] = __builtin_amdgcn_perm(u0[1], u0[0], 0x07060302u);
                hu[1] = __builtin_amdgcn_perm(u0[3], u0[2], 0x07060302u);
                hu[2] = __builtin_amdgcn_perm(u1[1], u1[0], 0x07060302u);
                hu[3] = __builtin_amdgcn_perm(u1[3], u1[2], 0x07060302u);
                lu[0] = __builtin_amdgcn_perm(u0[1], u0[0], 0x05040100u);
                lu[1] = __builtin_amdgcn_perm(u0[3], u0[2], 0x05040100u);
                lu[2] = __builtin_amdgcn_perm(u1[1], u1[0], 0x05040100u);
                lu[3] = __builtin_amdgcn_perm(u1[3], u1[2], 0x05040100u);
                bf16x8 sh = __builtin_bit_cast(bf16x8, hu);
                bf16x8 sl = __builtin_bit_cast(bf16x8, lu);
                #pragma unroll
                for (int tt = 0; tt < 2; ++tt) {
                    acc[c][tt] = __builtin_amdgcn_mfma_f32_16x16x32_bf16(wah[tt], sh, acc[c][tt], 0, 0, 0);
                    acc[c][tt] = __builtin_amdgcn_mfma_f32_16x16x32_bf16(wah[tt], sl, acc[c][tt], 0, 0, 0);
                    acc[c][tt] = __builtin_amdgcn_mfma_f32_16x16x32_bf16(wal[tt], sh, acc[c][tt], 0, 0, 0);
                }
            }
        }
        __syncthreads();   // all waves done reading state for this layer

        // epilogue: rows = output units j = wv*32 + tt*16 + 4*kg + r, col = point lp
        float4 bb[2];
        bb[0] = ((const float4*)(bm + l * 256 + wv * 32))[kg];
        bb[1] = ((const float4*)(bm + l * 256 + wv * 32 + 16))[kg];
        float hv[2][4], s1v[2][4], s2v[2][4], s3v[2][4];
        #pragma unroll
        for (int tt = 0; tt < 2; ++tt)
        #pragma unroll
        for (int r = 0; r < 4; ++r) {
            float z = acc[0][tt][r] + (&bb[tt].x)[r];
            act_derivs(z, hv[tt][r], s1v[tt][r], s2v[tt][r], s3v[tt][r]);
        }

        // chain rule + packsplit + 4 b64 stores per comp (final pi layout, chunk wv)
        #pragma unroll
        for (int c = 0; c < C; ++c) {
            float ov[2][4];
            #pragma unroll
            for (int tt = 0; tt < 2; ++tt)
            #pragma unroll
            for (int r = 0; r < 4; ++r) {
                float s1 = s1v[tt][r], s2 = s2v[tt][r], s3 = s3v[tt][r];
                float ax = acc[1][tt][r], ay = acc[2][tt][r];
                float val;
                if (c == 0) val = hv[tt][r];
                else if (c == 1) val = s1 * ax;
                else if (c == 2) val = s1 * ay;
                else if constexpr (C == 10) {
                    float axx = acc[3][tt][r], axy = acc[4][tt][r], ayy = acc[5][tt][r];
                    float axxx = acc[6][tt][r], axxy = acc[7][tt][r];
                    float axyy = acc[8][tt][r], ayyy = acc[9][tt][r];
                    if (c == 3) val = s2 * ax * ax + s1 * axx;
                    else if (c == 4) val = s2 * ax * ay + s1 * axy;
                    else if (c == 5) val = s2 * ay * ay + s1 * ayy;
                    else if (c == 6) val = s3 * ax * ax * ax + 3.f * s2 * ax * axx + s1 * axxx;
                    else if (c == 7) val = s3 * ax * ax * ay + s2 * (2.f * ax * axy + ay * axx) + s1 * axxy;
                    else if (c == 8) val = s3 * ax * ay * ay + s2 * (2.f * ay * axy + ax * ayy) + s1 * axyy;
                    else val = s3 * ay * ay * ay + 3.f * s2 * ay * ayy + s1 * ayyy;
                } else val = 0.f;
                ov[tt][r] = val;
            }
            char* R = smem + (c * 8 + wv) * 2048;
            #pragma unroll
            for (int tt = 0; tt < 2; ++tt)
            #pragma unroll
            for (int rp = 0; rp < 2; ++rp) {
                int kggp = 2 * tt + rp;
                uint2 q;
                q.x = packsplit(ov[tt][rp * 2 + 0]);   // e' = 2*kg
                q.y = packsplit(ov[tt][rp * 2 + 1]);   // e' = 2*kg+1
                *(uint2*)(R + (lp + 16 * kggp) * 32 + kg * 8) = q;
            }
        }
        __syncthreads();   // state fully updated for next layer
    }

    // ---- final linear dots (wave wv handles k-chunk wv for all 16 points) ----
    {
        float wlv[8];
        #pragma unroll
        for (int ep = 0; ep < 8; ++ep)
            wlv[ep] = Wl[wv * 32 + kappa_of(kg, ep)];
        float part[DN];
        #pragma unroll
        for (int i = 0; i < DN; ++i) {
            int c = DF + i;
            const char* R = smem + (c * 8 + wv) * 2048 + lane * 32;
            uintx4 u0 = *(const uintx4*)R;
            uintx4 u1 = *(const uintx4*)(R + 16);
            float s = 0.f;
            #pragma unroll
            for (int e = 0; e < 4; ++e)
                s += (b2f((ushort)(u0[e] >> 16)) + b2f((ushort)(u0[e] & 0xffffu))) * wlv[e];
            #pragma unroll
            for (int e = 0; e < 4; ++e)
                s += (b2f((ushort)(u1[e] >> 16)) + b2f((ushort)(u1[e] & 0xffffu))) * wlv[4 + e];
            s += __shfl_xor(s, 16, 64);
            s += __shfl_xor(s, 32, 64);
            part[i] = s;
        }
        __syncthreads();   // all state reads done before scratch overwrite
        if (lane < 16) {
            float* sc = (float*)(smem + wv * 2048);
            #pragma unroll
            for (int i = 0; i < DN; ++i) sc[i * 16 + lane] = part[i];
        }
        __syncthreads();
        if (t < 16 * DN) {
            int p = t & 15, i = t >> 4;
            float s = 0.f;
            #pragma unroll
            for (int w = 0; w < 8; ++w)
                s += ((const float*)(smem + w * 2048))[i * 16 + p];
            if (ADDBL && i == 0) s += bl[0];
            P[(size_t)(p0 + p) * 16 + PB + i] = s;
        }
    }
}

// ---------- loss ----------
__global__ __launch_bounds__(256) void loss_partials(
    const float* __restrict__ P, const float* __restrict__ u,
    const float* __restrict__ v, const float* __restrict__ pr,
    const int* __restrict__ mask, float* __restrict__ partials)
{
    int i = blockIdx.x * 256 + threadIdx.x;
    float s[9];
    #pragma unroll
    for (int k = 0; k < 9; ++k) s[k] = 0.f;
    if (i < NPTS) {
        const float* Pi = P + (size_t)i * 16;
        float psix = Pi[0], psiy = Pi[1], psixx = Pi[2], psixy = Pi[3], psiyy = Pi[4];
        float psixxx = Pi[5], psixxy = Pi[6], psixyy = Pi[7], psiyyy = Pi[8];
        float pv = Pi[9], ppx = Pi[10], ppy = Pi[11];
        float up = psiy, vp = -psix;
        float u_x = psixy, u_y = psiyy, v_x = -psixx, v_y = -psixy;
        float u_xx = psixxy, u_yy = psiyyy, v_xx = -psixxx, v_yy = -psixyy;
        float f_u = 2.f * up * u_x + up * v_y + vp * u_y + ppx - NU_C * (u_xx + u_yy);
        float f_v = 2.f * vp * v_y + up * v_x + vp * u_x + ppy - NU_C * (v_xx + v_yy);
        float ut = u[i], vt = v[i], pt = pr[i];
        float m = mask[i] ? 1.f : 0.f;
        float du = ut - up, dv = vt - vp, dp = pt - pv;
        s[0] = m * du * du; s[1] = m * dv * dv; s[2] = m * dp * dp;
        s[3] = du * du;     s[4] = dv * dv;     s[5] = dp * dp;
        s[6] = f_u * f_u;   s[7] = f_v * f_v;   s[8] = m;
    }
    int lane = threadIdx.x & 63, wid = threadIdx.x >> 6;
    __shared__ float red[4][9];
    #pragma unroll
    for (int k = 0; k < 9; ++k) {
        float xv = s[k];
        #pragma unroll
        for (int off = 32; off; off >>= 1) xv += __shfl_down(xv, off, 64);
        s[k] = xv;
    }
    if (lane == 0) {
        #pragma unroll
        for (int k = 0; k < 9; ++k) red[wid][k] = s[k];
    }
    __syncthreads();
    if (threadIdx.x == 0) {
        #pragma unroll
        for (int k = 0; k < 9; ++k)
            partials[blockIdx.x * 9 + k] = red[0][k] + red[1][k] + red[2][k] + red[3][k];
    }
}

__global__ void loss_final(const float* __restrict__ partials, float* __restrict__ out)
{
    int lane = threadIdx.x;
    float sums[9];
    #pragma unroll
    for (int k = 0; k < 9; ++k) {
        float xv = (lane < 32) ? partials[lane * 9 + k] : 0.f;
        #pragma unroll
        for (int off = 32; off; off >>= 1) xv += __shfl_down(xv, off, 64);
        sums[k] = xv;
    }
    if (lane == 0) {
        float ms = fmaxf(sums[8], 1.0f);
        float inv_n = 1.0f / (float)NPTS;
        float u_bc = sums[0] / ms, v_bc = sums[1] / ms, p_bc = sums[2] / ms;
        float u_tr = sums[3] * inv_n, v_tr = sums[4] * inv_n, p_tr = sums[5] * inv_n;
        float rans = sums[6] * inv_n + sums[7] * inv_n;
        out[0] = u_bc + v_bc + rans;
        out[1] = p_bc + rans;
        out[2] = u_tr;
        out[3] = v_tr;
        out[4] = p_tr;
        out[5] = rans;
    }
}

extern "C" void kernel_launch(void* const* d_in, const int* in_sizes, int n_in,
                              void* d_out, int out_size, void* d_ws, size_t ws_size,
                              hipStream_t stream)
{
    (void)in_sizes; (void)n_in; (void)out_size; (void)ws_size;
    const float* x    = (const float*)d_in[0];
    const float* y    = (const float*)d_in[1];
    const float* u    = (const float*)d_in[2];
    const float* v    = (const float*)d_in[3];
    const float* pr   = (const float*)d_in[4];
    const int*   mask = (const int*)d_in[5];
    const float* psi_W0 = (const float*)d_in[6];
    const float* psi_b0 = (const float*)d_in[7];
    const float* psi_Wm = (const float*)d_in[8];
    const float* psi_bm = (const float*)d_in[9];
    const float* psi_Wl = (const float*)d_in[10];
    const float* psi_bl = (const float*)d_in[11];
    const float* p_W0 = (const float*)d_in[12];
    const float* p_b0 = (const float*)d_in[13];
    const float* p_Wm = (const float*)d_in[14];
    const float* p_bm = (const float*)d_in[15];
    const float* p_Wl = (const float*)d_in[16];
    const float* p_bl = (const float*)d_in[17];

    float*  P        = (float*)d_ws;                 // NPTS*16
    float*  partials = P + (size_t)NPTS * 16;        // 512
    ushort* Wfh      = (ushort*)(partials + 512);    // 18*65536
    ushort* Wfl      = Wfh + (size_t)18 * 65536;

    wprep<<<144, 256, 0, stream>>>(psi_Wm, p_Wm, Wfh, Wfl);

    // psi net: 10 comps, dots over comps 1..9 -> P slots 0..8
    fused_net<10, 1, 9, 0, false><<<NPTS / 16, 512, 10 * 16384, stream>>>(
        x, y, psi_W0, psi_b0, Wfh, Wfl, psi_bm, psi_Wl, psi_bl, P);

    // p net: 3 comps, dots over comps 0..2 -> P slots 9..11 (+bl on value)
    fused_net<3, 0, 3, 9, true><<<NPTS / 16, 512, 3 * 16384, stream>>>(
        x, y, p_W0, p_b0, Wfh + (size_t)9 * 65536, Wfl + (size_t)9 * 65536,
        p_bm, p_Wl, p_bl, P);

    loss_partials<<<NPTS / 256, 256, 0, stream>>>(P, u, v, pr, mask, partials);
    loss_final<<<1, 64, 0, stream>>>(partials, (float*)d_out);
}

// Round 10
// 436.666 us; speedup vs baseline: 5.2497x; 1.0708x over previous
//
#include <hip/hip_runtime.h>
#include <hip/hip_bf16.h>
#include <math.h>

#define HIDDEN 256
#define NPTS 8192
#define NMID_L 9
#define NU_C 0.01f

typedef __attribute__((ext_vector_type(8))) short bf16x8;
typedef __attribute__((ext_vector_type(4))) float floatx4;

// ---------- bf16 helpers ----------
__device__ __forceinline__ ushort f2b(float a) {
    unsigned x = __float_as_uint(a);
    return (ushort)((x + 0x7fffu + ((x >> 16) & 1u)) >> 16);
}
__device__ __forceinline__ float b2f(ushort u) {
    return __uint_as_float(((unsigned)u) << 16);
}
__device__ __forceinline__ void split2(float a, ushort& hi, ushort& lo) {
    ushort h = f2b(a);
    lo = f2b(a - b2f(h));
    hi = h;
}

// k-permutation pi (identical on A-frags (wprep) and B-frags (state)):
// slot (kgg, e') holds kappa = 16*(kgg>>1) + 4*(e'>>1) + 2*(kgg&1) + (e'&1)
__device__ __forceinline__ int kappa_of(int kgg, int ep) {
    return 16 * (kgg >> 1) + 4 * (ep >> 1) + 2 * (kgg & 1) + (ep & 1);
}

// softplus100 value + first three derivatives.
__device__ __forceinline__ void act_derivs(float z, float& h, float& s1, float& s2, float& s3)
{
    float t = 100.0f * z;
    float at = fabsf(t);
    float e = __expf(-at);
    float r = __builtin_amdgcn_rcpf(1.0f + e);
    float a_ = e * r;
    bool pos = (t >= 0.0f);
    float s   = pos ? r  : a_;
    float oms = pos ? a_ : r;
    float sp = fmaxf(t, 0.0f) - __logf(r);
    h  = 0.01f * sp;
    s1 = s;
    s2 = 100.0f * s * oms;
    s3 = s2 * (100.0f - 200.0f * s);
}

// ---------- weight prep: W[k][n] -> A-fragment layout (W as MFMA A operand) ----
__global__ __launch_bounds__(256) void wprep(const float* __restrict__ psi_Wm,
                                             const float* __restrict__ p_Wm,
                                             ushort* __restrict__ Wfh, ushort* __restrict__ Wfl)
{
    int bid = blockIdx.x;          // 18*8 = 144 blocks
    int l = bid >> 3, wv = bid & 7;
    const float* W = (l < 9) ? (psi_Wm + (size_t)l * 65536)
                             : (p_Wm + (size_t)(l - 9) * 65536);
    int t = threadIdx.x;
    int lane = t & 63;
    int m = lane & 15, kgg = lane >> 4;
    int grp = t >> 6;
    bf16x8* oh = (bf16x8*)Wfh;
    bf16x8* ol = (bf16x8*)Wfl;
    #pragma unroll
    for (int gi = 0; gi < 4; ++gi) {
        int gid = grp * 4 + gi;     // 0..15
        int tt = gid >> 3, ch = gid & 7;
        int n = wv * 32 + tt * 16 + m;
        bf16x8 vh, vl;
        #pragma unroll
        for (int ep = 0; ep < 8; ++ep) {
            int k = ch * 32 + kappa_of(kgg, ep);
            ushort hh, ll;
            split2(W[(size_t)k * HIDDEN + n], hh, ll);
            vh[ep] = (short)hh;
            vl[ep] = (short)ll;
        }
        size_t fidx = ((((size_t)l * 8 + wv) * 2 + tt) * 8 + ch) * 64 + lane;
        oh[fidx] = vh;
        ol[fidx] = vl;
    }
}

// ---------- fused whole-net kernel (operand-swapped; hi/lo split state) --------
// 512 thr = 8 waves; block owns 16 points. State region (c,ch) = 2 KB:
// hi B-frags at [0,1024), lo at [1024,2048), each read as lane*16 -> wave covers
// a contiguous 1024 B span = conflict-free ds_read_b128 (refined r9 rule).
// Frag elem e' of lane (pt + 16*kgg) = state k-in-chunk kappa(kgg,e').
// Epilogue: thread (lp,kg) owns rows j = wv*32 + tt*16 + 4*kg + r, col lp;
// pi maps (tt,r) -> kggp = 2*tt+(r>>1), e' = 2*kg+(r&1): 8 b32 writes/comp,
// word = 4*lp + kg (+64*kggp) -> 2 lanes/bank = free. No bounce, no perms.
template<int C, int DF, int DN, int PB, bool ADDBL>
__global__ __launch_bounds__(512, 2) void fused_net(
    const float* __restrict__ x, const float* __restrict__ y,
    const float* __restrict__ W0, const float* __restrict__ b0,
    const ushort* __restrict__ Wfh, const ushort* __restrict__ Wfl,
    const float* __restrict__ bm,
    const float* __restrict__ Wl, const float* __restrict__ bl,
    float* __restrict__ P)
{
    extern __shared__ char smem[];
    const int t = threadIdx.x;
    const int lane = t & 63;
    const int wv = t >> 6;
    const int p0 = blockIdx.x * 16;
    const int lp = lane & 15;       // point
    const int kg = lane >> 4;       // k-quad index

    // ---- layer 0: jet init straight into pi-packed hi/lo state ----
    {
        float xx = x[p0 + lp];
        float yy = y[p0 + lp];
        #pragma unroll
        for (int e = 0; e < 8; e += 2) {
            float vals2[C][2];
            #pragma unroll
            for (int ee = 0; ee < 2; ++ee) {
                int j = wv * 32 + kg * 8 + e + ee;
                float ax = W0[j];
                float ay = W0[HIDDEN + j];
                float a = xx * ax + yy * ay + b0[j];
                float h, s1, s2, s3;
                act_derivs(a, h, s1, s2, s3);
                vals2[0][ee] = h; vals2[1][ee] = s1 * ax; vals2[2][ee] = s1 * ay;
                if constexpr (C == 10) {
                    vals2[3][ee] = s2 * ax * ax;
                    vals2[4][ee] = s2 * ax * ay;
                    vals2[5][ee] = s2 * ay * ay;
                    vals2[6][ee] = s3 * ax * ax * ax;
                    vals2[7][ee] = s3 * ax * ax * ay;
                    vals2[8][ee] = s3 * ax * ay * ay;
                    vals2[9][ee] = s3 * ay * ay * ay;
                }
            }
            int kap = kg * 8 + e;                       // even
            int kgg = 2 * (kap >> 4) + ((kap >> 1) & 1);
            int ep  = 2 * ((kap >> 2) & 3);             // kap, kap+1 -> ep, ep+1
            #pragma unroll
            for (int c = 0; c < C; ++c) {
                char* R = smem + (c * 8 + wv) * 2048;
                ushort h0, l0, h1, l1;
                split2(vals2[c][0], h0, l0);
                split2(vals2[c][1], h1, l1);
                *(unsigned*)(R + (lp + 16 * kgg) * 16 + ep * 2) =
                    ((unsigned)h1 << 16) | h0;
                *(unsigned*)(R + 1024 + (lp + 16 * kgg) * 16 + ep * 2) =
                    ((unsigned)l1 << 16) | l0;
            }
        }
    }
    __syncthreads();

    const bf16x8* WfhV = (const bf16x8*)Wfh;
    const bf16x8* WflV = (const bf16x8*)Wfl;

    // ---- 9 hidden layers ----
    for (int l = 0; l < NMID_L; ++l) {
        floatx4 acc[C][2];
        #pragma unroll
        for (int c = 0; c < C; ++c) {
            acc[c][0] = (floatx4){0.f, 0.f, 0.f, 0.f};
            acc[c][1] = (floatx4){0.f, 0.f, 0.f, 0.f};
        }
        const size_t wbase = ((size_t)l * 8 + wv) * 1024;
        #pragma unroll
        for (int ch = 0; ch < 8; ++ch) {
            bf16x8 wah[2], wal[2];          // A = weights (this wave's 2 row-tiles)
            #pragma unroll
            for (int tt = 0; tt < 2; ++tt) {
                size_t bi = wbase + ((size_t)tt * 8 + ch) * 64 + lane;
                wah[tt] = WfhV[bi];
                wal[tt] = WflV[bi];
            }
            #pragma unroll
            for (int c = 0; c < C; ++c) {
                const char* R = smem + (c * 8 + ch) * 2048 + lane * 16;  // CONTIGUOUS
                bf16x8 sh = *(const bf16x8*)R;
                bf16x8 sl = *(const bf16x8*)(R + 1024);
                #pragma unroll
                for (int tt = 0; tt < 2; ++tt) {
                    acc[c][tt] = __builtin_amdgcn_mfma_f32_16x16x32_bf16(wah[tt], sh, acc[c][tt], 0, 0, 0);
                    acc[c][tt] = __builtin_amdgcn_mfma_f32_16x16x32_bf16(wah[tt], sl, acc[c][tt], 0, 0, 0);
                    acc[c][tt] = __builtin_amdgcn_mfma_f32_16x16x32_bf16(wal[tt], sh, acc[c][tt], 0, 0, 0);
                }
            }
        }
        __syncthreads();   // all waves done reading state for this layer

        // epilogue: rows = output units j = wv*32 + tt*16 + 4*kg + r, col = point lp
        float4 bb[2];
        bb[0] = ((const float4*)(bm + l * 256 + wv * 32))[kg];
        bb[1] = ((const float4*)(bm + l * 256 + wv * 32 + 16))[kg];
        float hv[2][4], s1v[2][4], s2v[2][4], s3v[2][4];
        #pragma unroll
        for (int tt = 0; tt < 2; ++tt)
        #pragma unroll
        for (int r = 0; r < 4; ++r) {
            float z = acc[0][tt][r] + (&bb[tt].x)[r];
            act_derivs(z, hv[tt][r], s1v[tt][r], s2v[tt][r], s3v[tt][r]);
        }

        // chain rule + split + 8 b32 stores per comp (final pi layout, chunk wv)
        #pragma unroll
        for (int c = 0; c < C; ++c) {
            float ov[2][4];
            #pragma unroll
            for (int tt = 0; tt < 2; ++tt)
            #pragma unroll
            for (int r = 0; r < 4; ++r) {
                float s1 = s1v[tt][r], s2 = s2v[tt][r], s3 = s3v[tt][r];
                float ax = acc[1][tt][r], ay = acc[2][tt][r];
                float val;
                if (c == 0) val = hv[tt][r];
                else if (c == 1) val = s1 * ax;
                else if (c == 2) val = s1 * ay;
                else if constexpr (C == 10) {
                    float axx = acc[3][tt][r], axy = acc[4][tt][r], ayy = acc[5][tt][r];
                    float axxx = acc[6][tt][r], axxy = acc[7][tt][r];
                    float axyy = acc[8][tt][r], ayyy = acc[9][tt][r];
                    if (c == 3) val = s2 * ax * ax + s1 * axx;
                    else if (c == 4) val = s2 * ax * ay + s1 * axy;
                    else if (c == 5) val = s2 * ay * ay + s1 * ayy;
                    else if (c == 6) val = s3 * ax * ax * ax + 3.f * s2 * ax * axx + s1 * axxx;
                    else if (c == 7) val = s3 * ax * ax * ay + s2 * (2.f * ax * axy + ay * axx) + s1 * axxy;
                    else if (c == 8) val = s3 * ax * ay * ay + s2 * (2.f * ay * axy + ax * ayy) + s1 * axyy;
                    else val = s3 * ay * ay * ay + 3.f * s2 * ay * ayy + s1 * ayyy;
                } else val = 0.f;
                ov[tt][r] = val;
            }
            char* R = smem + (c * 8 + wv) * 2048;
            #pragma unroll
            for (int tt = 0; tt < 2; ++tt)
            #pragma unroll
            for (int rp = 0; rp < 2; ++rp) {
                int kggp = 2 * tt + rp;
                ushort h0, l0, h1, l1;
                split2(ov[tt][rp * 2 + 0], h0, l0);   // e' = 2*kg
                split2(ov[tt][rp * 2 + 1], h1, l1);   // e' = 2*kg+1
                *(unsigned*)(R + (lp + 16 * kggp) * 16 + kg * 4) =
                    ((unsigned)h1 << 16) | h0;
                *(unsigned*)(R + 1024 + (lp + 16 * kggp) * 16 + kg * 4) =
                    ((unsigned)l1 << 16) | l0;
            }
        }
        __syncthreads();   // state fully updated for next layer
    }

    // ---- final linear dots (wave wv handles k-chunk wv for all 16 points) ----
    {
        float wlv[8];
        #pragma unroll
        for (int ep = 0; ep < 8; ++ep)
            wlv[ep] = Wl[wv * 32 + kappa_of(kg, ep)];
        float part[DN];
        #pragma unroll
        for (int i = 0; i < DN; ++i) {
            int c = DF + i;
            const char* R = smem + (c * 8 + wv) * 2048 + lane * 16;
            bf16x8 vh = *(const bf16x8*)R;
            bf16x8 vl = *(const bf16x8*)(R + 1024);
            float s = 0.f;
            #pragma unroll
            for (int e = 0; e < 8; ++e)
                s += (b2f((ushort)vh[e]) + b2f((ushort)vl[e])) * wlv[e];
            s += __shfl_xor(s, 16, 64);
            s += __shfl_xor(s, 32, 64);
            part[i] = s;
        }
        __syncthreads();   // all state reads done before scratch overwrite
        if (lane < 16) {
            float* sc = (float*)(smem + wv * 2048);
            #pragma unroll
            for (int i = 0; i < DN; ++i) sc[i * 16 + lane] = part[i];
        }
        __syncthreads();
        if (t < 16 * DN) {
            int p = t & 15, i = t >> 4;
            float s = 0.f;
            #pragma unroll
            for (int w = 0; w < 8; ++w)
                s += ((const float*)(smem + w * 2048))[i * 16 + p];
            if (ADDBL && i == 0) s += bl[0];
            P[(size_t)(p0 + p) * 16 + PB + i] = s;
        }
    }
}

// ---------- loss ----------
__global__ __launch_bounds__(256) void loss_partials(
    const float* __restrict__ P, const float* __restrict__ u,
    const float* __restrict__ v, const float* __restrict__ pr,
    const int* __restrict__ mask, float* __restrict__ partials)
{
    int i = blockIdx.x * 256 + threadIdx.x;
    float s[9];
    #pragma unroll
    for (int k = 0; k < 9; ++k) s[k] = 0.f;
    if (i < NPTS) {
        const float* Pi = P + (size_t)i * 16;
        float psix = Pi[0], psiy = Pi[1], psixx = Pi[2], psixy = Pi[3], psiyy = Pi[4];
        float psixxx = Pi[5], psixxy = Pi[6], psixyy = Pi[7], psiyyy = Pi[8];
        float pv = Pi[9], ppx = Pi[10], ppy = Pi[11];
        float up = psiy, vp = -psix;
        float u_x = psixy, u_y = psiyy, v_x = -psixx, v_y = -psixy;
        float u_xx = psixxy, u_yy = psiyyy, v_xx = -psixxx, v_yy = -psixyy;
        float f_u = 2.f * up * u_x + up * v_y + vp * u_y + ppx - NU_C * (u_xx + u_yy);
        float f_v = 2.f * vp * v_y + up * v_x + vp * u_x + ppy - NU_C * (v_xx + v_yy);
        float ut = u[i], vt = v[i], pt = pr[i];
        float m = mask[i] ? 1.f : 0.f;
        float du = ut - up, dv = vt - vp, dp = pt - pv;
        s[0] = m * du * du; s[1] = m * dv * dv; s[2] = m * dp * dp;
        s[3] = du * du;     s[4] = dv * dv;     s[5] = dp * dp;
        s[6] = f_u * f_u;   s[7] = f_v * f_v;   s[8] = m;
    }
    int lane = threadIdx.x & 63, wid = threadIdx.x >> 6;
    __shared__ float red[4][9];
    #pragma unroll
    for (int k = 0; k < 9; ++k) {
        float xv = s[k];
        #pragma unroll
        for (int off = 32; off; off >>= 1) xv += __shfl_down(xv, off, 64);
        s[k] = xv;
    }
    if (lane == 0) {
        #pragma unroll
        for (int k = 0; k < 9; ++k) red[wid][k] = s[k];
    }
    __syncthreads();
    if (threadIdx.x == 0) {
        #pragma unroll
        for (int k = 0; k < 9; ++k)
            partials[blockIdx.x * 9 + k] = red[0][k] + red[1][k] + red[2][k] + red[3][k];
    }
}

__global__ void loss_final(const float* __restrict__ partials, float* __restrict__ out)
{
    int lane = threadIdx.x;
    float sums[9];
    #pragma unroll
    for (int k = 0; k < 9; ++k) {
        float xv = (lane < 32) ? partials[lane * 9 + k] : 0.f;
        #pragma unroll
        for (int off = 32; off; off >>= 1) xv += __shfl_down(xv, off, 64);
        sums[k] = xv;
    }
    if (lane == 0) {
        float ms = fmaxf(sums[8], 1.0f);
        float inv_n = 1.0f / (float)NPTS;
        float u_bc = sums[0] / ms, v_bc = sums[1] / ms, p_bc = sums[2] / ms;
        float u_tr = sums[3] * inv_n, v_tr = sums[4] * inv_n, p_tr = sums[5] * inv_n;
        float rans = sums[6] * inv_n + sums[7] * inv_n;
        out[0] = u_bc + v_bc + rans;
        out[1] = p_bc + rans;
        out[2] = u_tr;
        out[3] = v_tr;
        out[4] = p_tr;
        out[5] = rans;
    }
}

extern "C" void kernel_launch(void* const* d_in, const int* in_sizes, int n_in,
                              void* d_out, int out_size, void* d_ws, size_t ws_size,
                              hipStream_t stream)
{
    (void)in_sizes; (void)n_in; (void)out_size; (void)ws_size;
    const float* x    = (const float*)d_in[0];
    const float* y    = (const float*)d_in[1];
    const float* u    = (const float*)d_in[2];
    const float* v    = (const float*)d_in[3];
    const float* pr   = (const float*)d_in[4];
    const int*   mask = (const int*)d_in[5];
    const float* psi_W0 = (const float*)d_in[6];
    const float* psi_b0 = (const float*)d_in[7];
    const float* psi_Wm = (const float*)d_in[8];
    const float* psi_bm = (const float*)d_in[9];
    const float* psi_Wl = (const float*)d_in[10];
    const float* psi_bl = (const float*)d_in[11];
    const float* p_W0 = (const float*)d_in[12];
    const float* p_b0 = (const float*)d_in[13];
    const float* p_Wm = (const float*)d_in[14];
    const float* p_bm = (const float*)d_in[15];
    const float* p_Wl = (const float*)d_in[16];
    const float* p_bl = (const float*)d_in[17];

    float*  P        = (float*)d_ws;                 // NPTS*16
    float*  partials = P + (size_t)NPTS * 16;        // 512
    ushort* Wfh      = (ushort*)(partials + 512);    // 18*65536
    ushort* Wfl      = Wfh + (size_t)18 * 65536;

    wprep<<<144, 256, 0, stream>>>(psi_Wm, p_Wm, Wfh, Wfl);

    // psi net: 10 comps, dots over comps 1..9 -> P slots 0..8
    fused_net<10, 1, 9, 0, false><<<NPTS / 16, 512, 10 * 16384, stream>>>(
        x, y, psi_W0, psi_b0, Wfh, Wfl, psi_bm, psi_Wl, psi_bl, P);

    // p net: 3 comps, dots over comps 0..2 -> P slots 9..11 (+bl on value)
    fused_net<3, 0, 3, 9, true><<<NPTS / 16, 512, 3 * 16384, stream>>>(
        x, y, p_W0, p_b0, Wfh + (size_t)9 * 65536, Wfl + (size_t)9 * 65536,
        p_bm, p_Wl, p_bl, P);

    loss_partials<<<NPTS / 256, 256, 0, stream>>>(P, u, v, pr, mask, partials);
    loss_final<<<1, 64, 0, stream>>>(partials, (float*)d_out);
}

// Round 11
// 411.190 us; speedup vs baseline: 5.5749x; 1.0620x over previous
//
#include <hip/hip_runtime.h>
#include <hip/hip_bf16.h>
#include <math.h>

#define HIDDEN 256
#define NPTS 8192
#define NMID_L 9
#define NU_C 0.01f

typedef __attribute__((ext_vector_type(8))) short bf16x8;
typedef __attribute__((ext_vector_type(4))) float floatx4;

// ---------- bf16 helpers ----------
__device__ __forceinline__ ushort f2b(float a) {
    unsigned x = __float_as_uint(a);
    return (ushort)((x + 0x7fffu + ((x >> 16) & 1u)) >> 16);
}
__device__ __forceinline__ float b2f(ushort u) {
    return __uint_as_float(((unsigned)u) << 16);
}
__device__ __forceinline__ void split2(float a, ushort& hi, ushort& lo) {
    ushort h = f2b(a);
    lo = f2b(a - b2f(h));
    hi = h;
}
// Truncation-based pair split: values (a0,a1) -> packed hi word (h1<<16|h0) and
// lo word (l1<<16|l0). hi = trunc-to-bf16 (mask), lo = trunc(a - hi): residual
// ~2^-16 rel — far inside budget. 6 VALU ops per pair (2 AND, 2 SUB, 2 PERM).
__device__ __forceinline__ void packpair(float a0, float a1, unsigned& wh, unsigned& wl) {
    unsigned x0 = __float_as_uint(a0), x1 = __float_as_uint(a1);
    float h0 = __uint_as_float(x0 & 0xffff0000u);
    float h1 = __uint_as_float(x1 & 0xffff0000u);
    unsigned l0 = __float_as_uint(a0 - h0);
    unsigned l1 = __float_as_uint(a1 - h1);
    wh = __builtin_amdgcn_perm(x1, x0, 0x07060302u);
    wl = __builtin_amdgcn_perm(l1, l0, 0x07060302u);
}

// k-permutation pi (identical on A-frags (wprep) and B-frags (state)):
// slot (kgg, e') holds kappa = 16*(kgg>>1) + 4*(e'>>1) + 2*(kgg&1) + (e'&1)
__device__ __forceinline__ int kappa_of(int kgg, int ep) {
    return 16 * (kgg >> 1) + 4 * (ep >> 1) + 2 * (kgg & 1) + (ep & 1);
}

// softplus100 value + first three derivatives.
__device__ __forceinline__ void act_derivs(float z, float& h, float& s1, float& s2, float& s3)
{
    float t = 100.0f * z;
    float at = fabsf(t);
    float e = __expf(-at);
    float r = __builtin_amdgcn_rcpf(1.0f + e);
    float a_ = e * r;
    bool pos = (t >= 0.0f);
    float s   = pos ? r  : a_;
    float oms = pos ? a_ : r;
    float sp = fmaxf(t, 0.0f) - __logf(r);
    h  = 0.01f * sp;
    s1 = s;
    s2 = 100.0f * s * oms;
    s3 = s2 * (100.0f - 200.0f * s);
}

// ---------- weight prep: W[k][n] -> A-fragment layout (W as MFMA A operand) ----
__global__ __launch_bounds__(256) void wprep(const float* __restrict__ psi_Wm,
                                             const float* __restrict__ p_Wm,
                                             ushort* __restrict__ Wfh, ushort* __restrict__ Wfl)
{
    int bid = blockIdx.x;          // 18*8 = 144 blocks
    int l = bid >> 3, wv = bid & 7;
    const float* W = (l < 9) ? (psi_Wm + (size_t)l * 65536)
                             : (p_Wm + (size_t)(l - 9) * 65536);
    int t = threadIdx.x;
    int lane = t & 63;
    int m = lane & 15, kgg = lane >> 4;
    int grp = t >> 6;
    bf16x8* oh = (bf16x8*)Wfh;
    bf16x8* ol = (bf16x8*)Wfl;
    #pragma unroll
    for (int gi = 0; gi < 4; ++gi) {
        int gid = grp * 4 + gi;     // 0..15
        int tt = gid >> 3, ch = gid & 7;
        int n = wv * 32 + tt * 16 + m;
        bf16x8 vh, vl;
        #pragma unroll
        for (int ep = 0; ep < 8; ++ep) {
            int k = ch * 32 + kappa_of(kgg, ep);
            ushort hh, ll;
            split2(W[(size_t)k * HIDDEN + n], hh, ll);
            vh[ep] = (short)hh;
            vl[ep] = (short)ll;
        }
        size_t fidx = ((((size_t)l * 8 + wv) * 2 + tt) * 8 + ch) * 64 + lane;
        oh[fidx] = vh;
        ol[fidx] = vl;
    }
}

// ---------- fused whole-net kernel (operand-swapped; hi/lo split state) --------
// 512 thr = 8 waves; block owns 16 points. State region (c,ch) = 2 KB:
// hi B-frags at [0,1024), lo at [1024,2048), read as lane*16 (contiguous 1024 B
// per wave = conflict-free ds_read_b128). Frag elem e' of lane (pt + 16*kgg) =
// state k-in-chunk kappa(kgg,e'). Epilogue: thread (lp,kg) owns rows
// j = wv*32 + tt*16 + 4*kg + r, col lp; pi maps (tt,r) -> kggp = 2*tt+(r>>1),
// e' = 2*kg+(r&1): 8 b32 writes/comp at 2 lanes/bank (free). VALU via
// floatx4 (v_pk_fma) + trunc packpair.
template<int C, int DF, int DN, int PB, bool ADDBL>
__global__ __launch_bounds__(512, 2) void fused_net(
    const float* __restrict__ x, const float* __restrict__ y,
    const float* __restrict__ W0, const float* __restrict__ b0,
    const ushort* __restrict__ Wfh, const ushort* __restrict__ Wfl,
    const float* __restrict__ bm,
    const float* __restrict__ Wl, const float* __restrict__ bl,
    float* __restrict__ P)
{
    extern __shared__ char smem[];
    const int t = threadIdx.x;
    const int lane = t & 63;
    const int wv = t >> 6;
    const int p0 = blockIdx.x * 16;
    const int lp = lane & 15;       // point
    const int kg = lane >> 4;       // k-quad index

    // ---- layer 0: jet init straight into pi-packed hi/lo state ----
    {
        float xx = x[p0 + lp];
        float yy = y[p0 + lp];
        #pragma unroll
        for (int e = 0; e < 8; e += 2) {
            float vals2[C][2];
            #pragma unroll
            for (int ee = 0; ee < 2; ++ee) {
                int j = wv * 32 + kg * 8 + e + ee;
                float ax = W0[j];
                float ay = W0[HIDDEN + j];
                float a = xx * ax + yy * ay + b0[j];
                float h, s1, s2, s3;
                act_derivs(a, h, s1, s2, s3);
                vals2[0][ee] = h; vals2[1][ee] = s1 * ax; vals2[2][ee] = s1 * ay;
                if constexpr (C == 10) {
                    vals2[3][ee] = s2 * ax * ax;
                    vals2[4][ee] = s2 * ax * ay;
                    vals2[5][ee] = s2 * ay * ay;
                    vals2[6][ee] = s3 * ax * ax * ax;
                    vals2[7][ee] = s3 * ax * ax * ay;
                    vals2[8][ee] = s3 * ax * ay * ay;
                    vals2[9][ee] = s3 * ay * ay * ay;
                }
            }
            int kap = kg * 8 + e;                       // even
            int kgg = 2 * (kap >> 4) + ((kap >> 1) & 1);
            int ep  = 2 * ((kap >> 2) & 3);             // kap, kap+1 -> ep, ep+1
            #pragma unroll
            for (int c = 0; c < C; ++c) {
                char* R = smem + (c * 8 + wv) * 2048;
                unsigned wh, wl;
                packpair(vals2[c][0], vals2[c][1], wh, wl);
                *(unsigned*)(R + (lp + 16 * kgg) * 16 + ep * 2) = wh;
                *(unsigned*)(R + 1024 + (lp + 16 * kgg) * 16 + ep * 2) = wl;
            }
        }
    }
    __syncthreads();

    const bf16x8* WfhV = (const bf16x8*)Wfh;
    const bf16x8* WflV = (const bf16x8*)Wfl;

    // ---- 9 hidden layers ----
    for (int l = 0; l < NMID_L; ++l) {
        floatx4 acc[C][2];
        #pragma unroll
        for (int c = 0; c < C; ++c) {
            acc[c][0] = (floatx4){0.f, 0.f, 0.f, 0.f};
            acc[c][1] = (floatx4){0.f, 0.f, 0.f, 0.f};
        }
        const size_t wbase = ((size_t)l * 8 + wv) * 1024;
        #pragma unroll
        for (int ch = 0; ch < 8; ++ch) {
            bf16x8 wah[2], wal[2];          // A = weights (this wave's 2 row-tiles)
            #pragma unroll
            for (int tt = 0; tt < 2; ++tt) {
                size_t bi = wbase + ((size_t)tt * 8 + ch) * 64 + lane;
                wah[tt] = WfhV[bi];
                wal[tt] = WflV[bi];
            }
            #pragma unroll
            for (int c = 0; c < C; ++c) {
                const char* R = smem + (c * 8 + ch) * 2048 + lane * 16;  // CONTIGUOUS
                bf16x8 sh = *(const bf16x8*)R;
                bf16x8 sl = *(const bf16x8*)(R + 1024);
                #pragma unroll
                for (int tt = 0; tt < 2; ++tt) {
                    acc[c][tt] = __builtin_amdgcn_mfma_f32_16x16x32_bf16(wah[tt], sh, acc[c][tt], 0, 0, 0);
                    acc[c][tt] = __builtin_amdgcn_mfma_f32_16x16x32_bf16(wah[tt], sl, acc[c][tt], 0, 0, 0);
                    acc[c][tt] = __builtin_amdgcn_mfma_f32_16x16x32_bf16(wal[tt], sh, acc[c][tt], 0, 0, 0);
                }
            }
        }
        __syncthreads();   // all waves done reading state for this layer

        // epilogue: rows = output units j = wv*32 + tt*16 + 4*kg + r, col = point lp
        floatx4 hvq[2], s1q[2], s2q[2], s3q[2];
        #pragma unroll
        for (int tt = 0; tt < 2; ++tt) {
            floatx4 bbq = reinterpret_cast<const floatx4*>(bm + l * 256 + wv * 32 + tt * 16)[kg];
            floatx4 z4 = acc[0][tt] + bbq;
            #pragma unroll
            for (int r = 0; r < 4; ++r) {
                float h, s1, s2, s3;
                act_derivs(z4[r], h, s1, s2, s3);
                hvq[tt][r] = h; s1q[tt][r] = s1; s2q[tt][r] = s2; s3q[tt][r] = s3;
            }
        }

        // chain rule (floatx4 / v_pk) + trunc packpair + 8 b32 stores per comp
        #pragma unroll
        for (int c = 0; c < C; ++c) {
            char* R = smem + (c * 8 + wv) * 2048;
            #pragma unroll
            for (int tt = 0; tt < 2; ++tt) {
                floatx4 s1 = s1q[tt], s2 = s2q[tt], s3 = s3q[tt];
                floatx4 ax = acc[1][tt], ay = acc[2][tt];
                floatx4 v4;
                if (c == 0) v4 = hvq[tt];
                else if (c == 1) v4 = s1 * ax;
                else if (c == 2) v4 = s1 * ay;
                else if constexpr (C == 10) {
                    floatx4 axx = acc[3][tt], axy = acc[4][tt], ayy = acc[5][tt];
                    floatx4 axxx = acc[6][tt], axxy = acc[7][tt];
                    floatx4 axyy = acc[8][tt], ayyy = acc[9][tt];
                    if (c == 3) v4 = s2 * ax * ax + s1 * axx;
                    else if (c == 4) v4 = s2 * ax * ay + s1 * axy;
                    else if (c == 5) v4 = s2 * ay * ay + s1 * ayy;
                    else if (c == 6) v4 = s3 * ax * ax * ax + 3.f * s2 * ax * axx + s1 * axxx;
                    else if (c == 7) v4 = s3 * ax * ax * ay + s2 * (2.f * ax * axy + ay * axx) + s1 * axxy;
                    else if (c == 8) v4 = s3 * ax * ay * ay + s2 * (2.f * ay * axy + ax * ayy) + s1 * axyy;
                    else v4 = s3 * ay * ay * ay + 3.f * s2 * ay * ayy + s1 * ayyy;
                } else v4 = (floatx4){0.f, 0.f, 0.f, 0.f};
                #pragma unroll
                for (int rp = 0; rp < 2; ++rp) {
                    int kggp = 2 * tt + rp;
                    unsigned wh, wl;
                    packpair(v4[rp * 2 + 0], v4[rp * 2 + 1], wh, wl);   // e' = 2kg, 2kg+1
                    *(unsigned*)(R + (lp + 16 * kggp) * 16 + kg * 4) = wh;
                    *(unsigned*)(R + 1024 + (lp + 16 * kggp) * 16 + kg * 4) = wl;
                }
            }
        }
        __syncthreads();   // state fully updated for next layer
    }

    // ---- final linear dots (wave wv handles k-chunk wv for all 16 points) ----
    {
        float wlv[8];
        #pragma unroll
        for (int ep = 0; ep < 8; ++ep)
            wlv[ep] = Wl[wv * 32 + kappa_of(kg, ep)];
        float part[DN];
        #pragma unroll
        for (int i = 0; i < DN; ++i) {
            int c = DF + i;
            const char* R = smem + (c * 8 + wv) * 2048 + lane * 16;
            bf16x8 vh = *(const bf16x8*)R;
            bf16x8 vl = *(const bf16x8*)(R + 1024);
            float s = 0.f;
            #pragma unroll
            for (int e = 0; e < 8; ++e)
                s += (b2f((ushort)vh[e]) + b2f((ushort)vl[e])) * wlv[e];
            s += __shfl_xor(s, 16, 64);
            s += __shfl_xor(s, 32, 64);
            part[i] = s;
        }
        __syncthreads();   // all state reads done before scratch overwrite
        if (lane < 16) {
            float* sc = (float*)(smem + wv * 2048);
            #pragma unroll
            for (int i = 0; i < DN; ++i) sc[i * 16 + lane] = part[i];
        }
        __syncthreads();
        if (t < 16 * DN) {
            int p = t & 15, i = t >> 4;
            float s = 0.f;
            #pragma unroll
            for (int w = 0; w < 8; ++w)
                s += ((const float*)(smem + w * 2048))[i * 16 + p];
            if (ADDBL && i == 0) s += bl[0];
            P[(size_t)(p0 + p) * 16 + PB + i] = s;
        }
    }
}

// ---------- loss ----------
__global__ __launch_bounds__(256) void loss_partials(
    const float* __restrict__ P, const float* __restrict__ u,
    const float* __restrict__ v, const float* __restrict__ pr,
    const int* __restrict__ mask, float* __restrict__ partials)
{
    int i = blockIdx.x * 256 + threadIdx.x;
    float s[9];
    #pragma unroll
    for (int k = 0; k < 9; ++k) s[k] = 0.f;
    if (i < NPTS) {
        const float* Pi = P + (size_t)i * 16;
        float psix = Pi[0], psiy = Pi[1], psixx = Pi[2], psixy = Pi[3], psiyy = Pi[4];
        float psixxx = Pi[5], psixxy = Pi[6], psixyy = Pi[7], psiyyy = Pi[8];
        float pv = Pi[9], ppx = Pi[10], ppy = Pi[11];
        float up = psiy, vp = -psix;
        float u_x = psixy, u_y = psiyy, v_x = -psixx, v_y = -psixy;
        float u_xx = psixxy, u_yy = psiyyy, v_xx = -psixxx, v_yy = -psixyy;
        float f_u = 2.f * up * u_x + up * v_y + vp * u_y + ppx - NU_C * (u_xx + u_yy);
        float f_v = 2.f * vp * v_y + up * v_x + vp * u_x + ppy - NU_C * (v_xx + v_yy);
        float ut = u[i], vt = v[i], pt = pr[i];
        float m = mask[i] ? 1.f : 0.f;
        float du = ut - up, dv = vt - vp, dp = pt - pv;
        s[0] = m * du * du; s[1] = m * dv * dv; s[2] = m * dp * dp;
        s[3] = du * du;     s[4] = dv * dv;     s[5] = dp * dp;
        s[6] = f_u * f_u;   s[7] = f_v * f_v;   s[8] = m;
    }
    int lane = threadIdx.x & 63, wid = threadIdx.x >> 6;
    __shared__ float red[4][9];
    #pragma unroll
    for (int k = 0; k < 9; ++k) {
        float xv = s[k];
        #pragma unroll
        for (int off = 32; off; off >>= 1) xv += __shfl_down(xv, off, 64);
        s[k] = xv;
    }
    if (lane == 0) {
        #pragma unroll
        for (int k = 0; k < 9; ++k) red[wid][k] = s[k];
    }
    __syncthreads();
    if (threadIdx.x == 0) {
        #pragma unroll
        for (int k = 0; k < 9; ++k)
            partials[blockIdx.x * 9 + k] = red[0][k] + red[1][k] + red[2][k] + red[3][k];
    }
}

__global__ void loss_final(const float* __restrict__ partials, float* __restrict__ out)
{
    int lane = threadIdx.x;
    float sums[9];
    #pragma unroll
    for (int k = 0; k < 9; ++k) {
        float xv = (lane < 32) ? partials[lane * 9 + k] : 0.f;
        #pragma unroll
        for (int off = 32; off; off >>= 1) xv += __shfl_down(xv, off, 64);
        sums[k] = xv;
    }
    if (lane == 0) {
        float ms = fmaxf(sums[8], 1.0f);
        float inv_n = 1.0f / (float)NPTS;
        float u_bc = sums[0] / ms, v_bc = sums[1] / ms, p_bc = sums[2] / ms;
        float u_tr = sums[3] * inv_n, v_tr = sums[4] * inv_n, p_tr = sums[5] * inv_n;
        float rans = sums[6] * inv_n + sums[7] * inv_n;
        out[0] = u_bc + v_bc + rans;
        out[1] = p_bc + rans;
        out[2] = u_tr;
        out[3] = v_tr;
        out[4] = p_tr;
        out[5] = rans;
    }
}

extern "C" void kernel_launch(void* const* d_in, const int* in_sizes, int n_in,
                              void* d_out, int out_size, void* d_ws, size_t ws_size,
                              hipStream_t stream)
{
    (void)in_sizes; (void)n_in; (void)out_size; (void)ws_size;
    const float* x    = (const float*)d_in[0];
    const float* y    = (const float*)d_in[1];
    const float* u    = (const float*)d_in[2];
    const float* v    = (const float*)d_in[3];
    const float* pr   = (const float*)d_in[4];
    const int*   mask = (const int*)d_in[5];
    const float* psi_W0 = (const float*)d_in[6];
    const float* psi_b0 = (const float*)d_in[7];
    const float* psi_Wm = (const float*)d_in[8];
    const float* psi_bm = (const float*)d_in[9];
    const float* psi_Wl = (const float*)d_in[10];
    const float* psi_bl = (const float*)d_in[11];
    const float* p_W0 = (const float*)d_in[12];
    const float* p_b0 = (const float*)d_in[13];
    const float* p_Wm = (const float*)d_in[14];
    const float* p_bm = (const float*)d_in[15];
    const float* p_Wl = (const float*)d_in[16];
    const float* p_bl = (const float*)d_in[17];

    float*  P        = (float*)d_ws;                 // NPTS*16
    float*  partials = P + (size_t)NPTS * 16;        // 512
    ushort* Wfh      = (ushort*)(partials + 512);    // 18*65536
    ushort* Wfl      = Wfh + (size_t)18 * 65536;

    wprep<<<144, 256, 0, stream>>>(psi_Wm, p_Wm, Wfh, Wfl);

    // psi net: 10 comps, dots over comps 1..9 -> P slots 0..8
    fused_net<10, 1, 9, 0, false><<<NPTS / 16, 512, 10 * 16384, stream>>>(
        x, y, psi_W0, psi_b0, Wfh, Wfl, psi_bm, psi_Wl, psi_bl, P);

    // p net: 3 comps, dots over comps 0..2 -> P slots 9..11 (+bl on value)
    fused_net<3, 0, 3, 9, true><<<NPTS / 16, 512, 3 * 16384, stream>>>(
        x, y, p_W0, p_b0, Wfh + (size_t)9 * 65536, Wfl + (size_t)9 * 65536,
        p_bm, p_Wl, p_bl, P);

    loss_partials<<<NPTS / 256, 256, 0, stream>>>(P, u, v, pr, mask, partials);
    loss_final<<<1, 64, 0, stream>>>(partials, (float*)d_out);
}

// Round 12
// 379.885 us; speedup vs baseline: 6.0343x; 1.0824x over previous
//
#include <hip/hip_runtime.h>
#include <hip/hip_bf16.h>
#include <math.h>

#define HIDDEN 256
#define NPTS 8192
#define NMID_L 9
#define NU_C 0.01f

typedef __attribute__((ext_vector_type(8))) short bf16x8;
typedef __attribute__((ext_vector_type(4))) float floatx4;

// ---------- bf16 helpers ----------
__device__ __forceinline__ ushort f2b(float a) {
    unsigned x = __float_as_uint(a);
    return (ushort)((x + 0x7fffu + ((x >> 16) & 1u)) >> 16);
}
__device__ __forceinline__ float b2f(ushort u) {
    return __uint_as_float(((unsigned)u) << 16);
}
__device__ __forceinline__ void split2(float a, ushort& hi, ushort& lo) {
    ushort h = f2b(a);
    lo = f2b(a - b2f(h));
    hi = h;
}
// Truncation-based pair split -> packed hi word + lo word (residual exact).
__device__ __forceinline__ void packpair(float a0, float a1, unsigned& wh, unsigned& wl) {
    unsigned x0 = __float_as_uint(a0), x1 = __float_as_uint(a1);
    float h0 = __uint_as_float(x0 & 0xffff0000u);
    float h1 = __uint_as_float(x1 & 0xffff0000u);
    unsigned l0 = __float_as_uint(a0 - h0);
    unsigned l1 = __float_as_uint(a1 - h1);
    wh = __builtin_amdgcn_perm(x1, x0, 0x07060302u);
    wl = __builtin_amdgcn_perm(l1, l0, 0x07060302u);
}
// Rounded single-bf16 pair pack (for reduced-precision comps).
__device__ __forceinline__ unsigned packpair1(float a0, float a1) {
    return ((unsigned)f2b(a1) << 16) | (unsigned)f2b(a0);
}

// k-permutation pi (identical on A-frags (wprep) and B-frags (state)):
// slot (kgg, e') holds kappa = 16*(kgg>>1) + 4*(e'>>1) + 2*(kgg&1) + (e'&1)
__device__ __forceinline__ int kappa_of(int kgg, int ep) {
    return 16 * (kgg >> 1) + 4 * (ep >> 1) + 2 * (kgg & 1) + (ep & 1);
}

// State region base: c0-2 = 2 KB regions (hi@0, lo@+1024); c3+ = 1 KB (hi only).
// c is a fully-unrolled loop constant -> folds to immediates.
__device__ __forceinline__ char* region_of(char* smem, int c, int ch) {
    return (c < 3) ? (smem + (c * 8 + ch) * 2048)
                   : (smem + 49152 + ((c - 3) * 8 + ch) * 1024);
}

// softplus100 value + first three derivatives.
__device__ __forceinline__ void act_derivs(float z, float& h, float& s1, float& s2, float& s3)
{
    float t = 100.0f * z;
    float at = fabsf(t);
    float e = __expf(-at);
    float r = __builtin_amdgcn_rcpf(1.0f + e);
    float a_ = e * r;
    bool pos = (t >= 0.0f);
    float s   = pos ? r  : a_;
    float oms = pos ? a_ : r;
    float sp = fmaxf(t, 0.0f) - __logf(r);
    h  = 0.01f * sp;
    s1 = s;
    s2 = 100.0f * s * oms;
    s3 = s2 * (100.0f - 200.0f * s);
}

// ---------- weight prep: W[k][n] -> A-fragment layout (W as MFMA A operand) ----
__global__ __launch_bounds__(256) void wprep(const float* __restrict__ psi_Wm,
                                             const float* __restrict__ p_Wm,
                                             ushort* __restrict__ Wfh, ushort* __restrict__ Wfl)
{
    int bid = blockIdx.x;          // 18*8 = 144 blocks
    int l = bid >> 3, wv = bid & 7;
    const float* W = (l < 9) ? (psi_Wm + (size_t)l * 65536)
                             : (p_Wm + (size_t)(l - 9) * 65536);
    int t = threadIdx.x;
    int lane = t & 63;
    int m = lane & 15, kgg = lane >> 4;
    int grp = t >> 6;
    bf16x8* oh = (bf16x8*)Wfh;
    bf16x8* ol = (bf16x8*)Wfl;
    #pragma unroll
    for (int gi = 0; gi < 4; ++gi) {
        int gid = grp * 4 + gi;     // 0..15
        int tt = gid >> 3, ch = gid & 7;
        int n = wv * 32 + tt * 16 + m;
        bf16x8 vh, vl;
        #pragma unroll
        for (int ep = 0; ep < 8; ++ep) {
            int k = ch * 32 + kappa_of(kgg, ep);
            ushort hh, ll;
            split2(W[(size_t)k * HIDDEN + n], hh, ll);
            vh[ep] = (short)hh;
            vl[ep] = (short)ll;
        }
        size_t fidx = ((((size_t)l * 8 + wv) * 2 + tt) * 8 + ch) * 64 + lane;
        oh[fidx] = vh;
        ol[fidx] = vl;
    }
}

// ---------- fused whole-net kernel --------------------------------------------
// 512 thr = 8 waves; block owns 16 points. Operand-swapped MFMA (A = weights
// hi+lo; B = state). State comps c0-2 hi+lo (3 MFMA), c3+ hi-only bf16 (2 MFMA:
// full-W x bf16-state) -- safe because c3+ errors propagate only linearly and
// all outputs are means over 8192 points. Reads lane*16 contiguous (conflict-
// free); epilogue writes b32 at 2 lanes/bank (free).
template<int C, int DF, int DN, int PB, bool ADDBL>
__global__ __launch_bounds__(512, 2) void fused_net(
    const float* __restrict__ x, const float* __restrict__ y,
    const float* __restrict__ W0, const float* __restrict__ b0,
    const ushort* __restrict__ Wfh, const ushort* __restrict__ Wfl,
    const float* __restrict__ bm,
    const float* __restrict__ Wl, const float* __restrict__ bl,
    float* __restrict__ P)
{
    extern __shared__ char smem[];
    const int t = threadIdx.x;
    const int lane = t & 63;
    const int wv = t >> 6;
    const int p0 = blockIdx.x * 16;
    const int lp = lane & 15;       // point
    const int kg = lane >> 4;       // k-quad index

    // ---- layer 0: jet init straight into pi-packed state ----
    {
        float xx = x[p0 + lp];
        float yy = y[p0 + lp];
        #pragma unroll
        for (int e = 0; e < 8; e += 2) {
            float vals2[C][2];
            #pragma unroll
            for (int ee = 0; ee < 2; ++ee) {
                int j = wv * 32 + kg * 8 + e + ee;
                float ax = W0[j];
                float ay = W0[HIDDEN + j];
                float a = xx * ax + yy * ay + b0[j];
                float h, s1, s2, s3;
                act_derivs(a, h, s1, s2, s3);
                vals2[0][ee] = h; vals2[1][ee] = s1 * ax; vals2[2][ee] = s1 * ay;
                if constexpr (C == 10) {
                    vals2[3][ee] = s2 * ax * ax;
                    vals2[4][ee] = s2 * ax * ay;
                    vals2[5][ee] = s2 * ay * ay;
                    vals2[6][ee] = s3 * ax * ax * ax;
                    vals2[7][ee] = s3 * ax * ax * ay;
                    vals2[8][ee] = s3 * ax * ay * ay;
                    vals2[9][ee] = s3 * ay * ay * ay;
                }
            }
            int kap = kg * 8 + e;                       // even
            int kgg = 2 * (kap >> 4) + ((kap >> 1) & 1);
            int ep  = 2 * ((kap >> 2) & 3);             // kap, kap+1 -> ep, ep+1
            #pragma unroll
            for (int c = 0; c < C; ++c) {
                char* R = region_of(smem, c, wv);
                if (c < 3) {
                    unsigned wh, wl;
                    packpair(vals2[c][0], vals2[c][1], wh, wl);
                    *(unsigned*)(R + (lp + 16 * kgg) * 16 + ep * 2) = wh;
                    *(unsigned*)(R + 1024 + (lp + 16 * kgg) * 16 + ep * 2) = wl;
                } else {
                    *(unsigned*)(R + (lp + 16 * kgg) * 16 + ep * 2) =
                        packpair1(vals2[c][0], vals2[c][1]);
                }
            }
        }
    }
    __syncthreads();

    const bf16x8* WfhV = (const bf16x8*)Wfh;
    const bf16x8* WflV = (const bf16x8*)Wfl;

    // ---- 9 hidden layers ----
    for (int l = 0; l < NMID_L; ++l) {
        floatx4 acc[C][2];
        #pragma unroll
        for (int c = 0; c < C; ++c) {
            acc[c][0] = (floatx4){0.f, 0.f, 0.f, 0.f};
            acc[c][1] = (floatx4){0.f, 0.f, 0.f, 0.f};
        }
        const size_t wbase = ((size_t)l * 8 + wv) * 1024;
        #pragma unroll
        for (int ch = 0; ch < 8; ++ch) {
            bf16x8 wah[2], wal[2];          // A = weights (this wave's 2 row-tiles)
            #pragma unroll
            for (int tt = 0; tt < 2; ++tt) {
                size_t bi = wbase + ((size_t)tt * 8 + ch) * 64 + lane;
                wah[tt] = WfhV[bi];
                wal[tt] = WflV[bi];
            }
            #pragma unroll
            for (int c = 0; c < C; ++c) {
                const char* R = region_of(smem, c, ch) + lane * 16;  // CONTIGUOUS
                bf16x8 sh = *(const bf16x8*)R;
                if (c < 3) {
                    bf16x8 sl = *(const bf16x8*)(R + 1024);
                    #pragma unroll
                    for (int tt = 0; tt < 2; ++tt) {
                        acc[c][tt] = __builtin_amdgcn_mfma_f32_16x16x32_bf16(wah[tt], sh, acc[c][tt], 0, 0, 0);
                        acc[c][tt] = __builtin_amdgcn_mfma_f32_16x16x32_bf16(wah[tt], sl, acc[c][tt], 0, 0, 0);
                        acc[c][tt] = __builtin_amdgcn_mfma_f32_16x16x32_bf16(wal[tt], sh, acc[c][tt], 0, 0, 0);
                    }
                } else {
                    #pragma unroll
                    for (int tt = 0; tt < 2; ++tt) {
                        acc[c][tt] = __builtin_amdgcn_mfma_f32_16x16x32_bf16(wah[tt], sh, acc[c][tt], 0, 0, 0);
                        acc[c][tt] = __builtin_amdgcn_mfma_f32_16x16x32_bf16(wal[tt], sh, acc[c][tt], 0, 0, 0);
                    }
                }
            }
        }
        __syncthreads();   // all waves done reading state for this layer

        // epilogue: rows = output units j = wv*32 + tt*16 + 4*kg + r, col = point lp
        floatx4 hvq[2], s1q[2], s2q[2], s3q[2];
        #pragma unroll
        for (int tt = 0; tt < 2; ++tt) {
            floatx4 bbq = reinterpret_cast<const floatx4*>(bm + l * 256 + wv * 32 + tt * 16)[kg];
            floatx4 z4 = acc[0][tt] + bbq;
            #pragma unroll
            for (int r = 0; r < 4; ++r) {
                float h, s1, s2, s3;
                act_derivs(z4[r], h, s1, s2, s3);
                hvq[tt][r] = h; s1q[tt][r] = s1; s2q[tt][r] = s2; s3q[tt][r] = s3;
            }
        }

        // chain rule (floatx4 / v_pk) + pack + b32 stores (final pi layout, chunk wv)
        #pragma unroll
        for (int c = 0; c < C; ++c) {
            char* R = region_of(smem, c, wv);
            #pragma unroll
            for (int tt = 0; tt < 2; ++tt) {
                floatx4 s1 = s1q[tt], s2 = s2q[tt], s3 = s3q[tt];
                floatx4 ax = acc[1][tt], ay = acc[2][tt];
                floatx4 v4;
                if (c == 0) v4 = hvq[tt];
                else if (c == 1) v4 = s1 * ax;
                else if (c == 2) v4 = s1 * ay;
                else if constexpr (C == 10) {
                    floatx4 axx = acc[3][tt], axy = acc[4][tt], ayy = acc[5][tt];
                    floatx4 axxx = acc[6][tt], axxy = acc[7][tt];
                    floatx4 axyy = acc[8][tt], ayyy = acc[9][tt];
                    if (c == 3) v4 = s2 * ax * ax + s1 * axx;
                    else if (c == 4) v4 = s2 * ax * ay + s1 * axy;
                    else if (c == 5) v4 = s2 * ay * ay + s1 * ayy;
                    else if (c == 6) v4 = s3 * ax * ax * ax + 3.f * s2 * ax * axx + s1 * axxx;
                    else if (c == 7) v4 = s3 * ax * ax * ay + s2 * (2.f * ax * axy + ay * axx) + s1 * axxy;
                    else if (c == 8) v4 = s3 * ax * ay * ay + s2 * (2.f * ay * axy + ax * ayy) + s1 * axyy;
                    else v4 = s3 * ay * ay * ay + 3.f * s2 * ay * ayy + s1 * ayyy;
                } else v4 = (floatx4){0.f, 0.f, 0.f, 0.f};
                #pragma unroll
                for (int rp = 0; rp < 2; ++rp) {
                    int kggp = 2 * tt + rp;
                    if (c < 3) {
                        unsigned wh, wl;
                        packpair(v4[rp * 2 + 0], v4[rp * 2 + 1], wh, wl);   // e' = 2kg, 2kg+1
                        *(unsigned*)(R + (lp + 16 * kggp) * 16 + kg * 4) = wh;
                        *(unsigned*)(R + 1024 + (lp + 16 * kggp) * 16 + kg * 4) = wl;
                    } else {
                        *(unsigned*)(R + (lp + 16 * kggp) * 16 + kg * 4) =
                            packpair1(v4[rp * 2 + 0], v4[rp * 2 + 1]);
                    }
                }
            }
        }
        __syncthreads();   // state fully updated for next layer
    }

    // ---- final linear dots (wave wv handles k-chunk wv for all 16 points) ----
    {
        float wlv[8];
        #pragma unroll
        for (int ep = 0; ep < 8; ++ep)
            wlv[ep] = Wl[wv * 32 + kappa_of(kg, ep)];
        float part[DN];
        #pragma unroll
        for (int i = 0; i < DN; ++i) {
            int c = DF + i;
            const char* R = region_of(smem, c, wv) + lane * 16;
            bf16x8 vh = *(const bf16x8*)R;
            float s = 0.f;
            if (c < 3) {
                bf16x8 vl = *(const bf16x8*)(R + 1024);
                #pragma unroll
                for (int e = 0; e < 8; ++e)
                    s += (b2f((ushort)vh[e]) + b2f((ushort)vl[e])) * wlv[e];
            } else {
                #pragma unroll
                for (int e = 0; e < 8; ++e)
                    s += b2f((ushort)vh[e]) * wlv[e];
            }
            s += __shfl_xor(s, 16, 64);
            s += __shfl_xor(s, 32, 64);
            part[i] = s;
        }
        __syncthreads();   // all state reads done before scratch overwrite
        if (lane < 16) {
            float* sc = (float*)(smem + wv * 2048);
            #pragma unroll
            for (int i = 0; i < DN; ++i) sc[i * 16 + lane] = part[i];
        }
        __syncthreads();
        if (t < 16 * DN) {
            int p = t & 15, i = t >> 4;
            float s = 0.f;
            #pragma unroll
            for (int w = 0; w < 8; ++w)
                s += ((const float*)(smem + w * 2048))[i * 16 + p];
            if (ADDBL && i == 0) s += bl[0];
            P[(size_t)(p0 + p) * 16 + PB + i] = s;
        }
    }
}

// ---------- loss ----------
__global__ __launch_bounds__(256) void loss_partials(
    const float* __restrict__ P, const float* __restrict__ u,
    const float* __restrict__ v, const float* __restrict__ pr,
    const int* __restrict__ mask, float* __restrict__ partials)
{
    int i = blockIdx.x * 256 + threadIdx.x;
    float s[9];
    #pragma unroll
    for (int k = 0; k < 9; ++k) s[k] = 0.f;
    if (i < NPTS) {
        const float* Pi = P + (size_t)i * 16;
        float psix = Pi[0], psiy = Pi[1], psixx = Pi[2], psixy = Pi[3], psiyy = Pi[4];
        float psixxx = Pi[5], psixxy = Pi[6], psixyy = Pi[7], psiyyy = Pi[8];
        float pv = Pi[9], ppx = Pi[10], ppy = Pi[11];
        float up = psiy, vp = -psix;
        float u_x = psixy, u_y = psiyy, v_x = -psixx, v_y = -psixy;
        float u_xx = psixxy, u_yy = psiyyy, v_xx = -psixxx, v_yy = -psixyy;
        float f_u = 2.f * up * u_x + up * v_y + vp * u_y + ppx - NU_C * (u_xx + u_yy);
        float f_v = 2.f * vp * v_y + up * v_x + vp * u_x + ppy - NU_C * (v_xx + v_yy);
        float ut = u[i], vt = v[i], pt = pr[i];
        float m = mask[i] ? 1.f : 0.f;
        float du = ut - up, dv = vt - vp, dp = pt - pv;
        s[0] = m * du * du; s[1] = m * dv * dv; s[2] = m * dp * dp;
        s[3] = du * du;     s[4] = dv * dv;     s[5] = dp * dp;
        s[6] = f_u * f_u;   s[7] = f_v * f_v;   s[8] = m;
    }
    int lane = threadIdx.x & 63, wid = threadIdx.x >> 6;
    __shared__ float red[4][9];
    #pragma unroll
    for (int k = 0; k < 9; ++k) {
        float xv = s[k];
        #pragma unroll
        for (int off = 32; off; off >>= 1) xv += __shfl_down(xv, off, 64);
        s[k] = xv;
    }
    if (lane == 0) {
        #pragma unroll
        for (int k = 0; k < 9; ++k) red[wid][k] = s[k];
    }
    __syncthreads();
    if (threadIdx.x == 0) {
        #pragma unroll
        for (int k = 0; k < 9; ++k)
            partials[blockIdx.x * 9 + k] = red[0][k] + red[1][k] + red[2][k] + red[3][k];
    }
}

__global__ void loss_final(const float* __restrict__ partials, float* __restrict__ out)
{
    int lane = threadIdx.x;
    float sums[9];
    #pragma unroll
    for (int k = 0; k < 9; ++k) {
        float xv = (lane < 32) ? partials[lane * 9 + k] : 0.f;
        #pragma unroll
        for (int off = 32; off; off >>= 1) xv += __shfl_down(xv, off, 64);
        sums[k] = xv;
    }
    if (lane == 0) {
        float ms = fmaxf(sums[8], 1.0f);
        float inv_n = 1.0f / (float)NPTS;
        float u_bc = sums[0] / ms, v_bc = sums[1] / ms, p_bc = sums[2] / ms;
        float u_tr = sums[3] * inv_n, v_tr = sums[4] * inv_n, p_tr = sums[5] * inv_n;
        float rans = sums[6] * inv_n + sums[7] * inv_n;
        out[0] = u_bc + v_bc + rans;
        out[1] = p_bc + rans;
        out[2] = u_tr;
        out[3] = v_tr;
        out[4] = p_tr;
        out[5] = rans;
    }
}

extern "C" void kernel_launch(void* const* d_in, const int* in_sizes, int n_in,
                              void* d_out, int out_size, void* d_ws, size_t ws_size,
                              hipStream_t stream)
{
    (void)in_sizes; (void)n_in; (void)out_size; (void)ws_size;
    const float* x    = (const float*)d_in[0];
    const float* y    = (const float*)d_in[1];
    const float* u    = (const float*)d_in[2];
    const float* v    = (const float*)d_in[3];
    const float* pr   = (const float*)d_in[4];
    const int*   mask = (const int*)d_in[5];
    const float* psi_W0 = (const float*)d_in[6];
    const float* psi_b0 = (const float*)d_in[7];
    const float* psi_Wm = (const float*)d_in[8];
    const float* psi_bm = (const float*)d_in[9];
    const float* psi_Wl = (const float*)d_in[10];
    const float* psi_bl = (const float*)d_in[11];
    const float* p_W0 = (const float*)d_in[12];
    const float* p_b0 = (const float*)d_in[13];
    const float* p_Wm = (const float*)d_in[14];
    const float* p_bm = (const float*)d_in[15];
    const float* p_Wl = (const float*)d_in[16];
    const float* p_bl = (const float*)d_in[17];

    float*  P        = (float*)d_ws;                 // NPTS*16
    float*  partials = P + (size_t)NPTS * 16;        // 512
    ushort* Wfh      = (ushort*)(partials + 512);    // 18*65536
    ushort* Wfl      = Wfh + (size_t)18 * 65536;

    wprep<<<144, 256, 0, stream>>>(psi_Wm, p_Wm, Wfh, Wfl);

    // psi net: 10 comps (c0-2 hi+lo, c3-9 hi-only), dots comps 1..9 -> P 0..8
    // LDS: 3*8*2048 + 7*8*1024 = 106496 B
    fused_net<10, 1, 9, 0, false><<<NPTS / 16, 512, 106496, stream>>>(
        x, y, psi_W0, psi_b0, Wfh, Wfl, psi_bm, psi_Wl, psi_bl, P);

    // p net: 3 comps (all hi+lo), dots comps 0..2 -> P 9..11 (+bl on value)
    fused_net<3, 0, 3, 9, true><<<NPTS / 16, 512, 49152, stream>>>(
        x, y, p_W0, p_b0, Wfh + (size_t)9 * 65536, Wfl + (size_t)9 * 65536,
        p_bm, p_Wl, p_bl, P);

    loss_partials<<<NPTS / 256, 256, 0, stream>>>(P, u, v, pr, mask, partials);
    loss_final<<<1, 64, 0, stream>>>(partials, (float*)d_out);
}